// Round 10
// baseline (173.581 us; speedup 1.0000x reference)
//
#include <hip/hip_runtime.h>

#define B_  2
#define L_  2048
#define D_  1024
#define H_  16
#define HD_ 64

typedef __attribute__((ext_vector_type(8))) short bf16x8;
typedef __attribute__((ext_vector_type(4))) float f32x4;
typedef __attribute__((ext_vector_type(16))) float f32x16;

#define MFMA16(a, b, c) __builtin_amdgcn_mfma_f32_16x16x32_bf16(a, b, c, 0, 0, 0)
#define MFMA32(a, b, c) __builtin_amdgcn_mfma_f32_32x32x16_bf16(a, b, c, 0, 0, 0)

__device__ __forceinline__ unsigned short f2bf(float f) {
    union { float f; unsigned u; } v; v.f = f;
    unsigned r = v.u + 0x7FFFu + ((v.u >> 16) & 1u);
    return (unsigned short)(r >> 16);
}

// pack two f32 -> one dword of 2 bf16 (truncation); elem0 (low16) = a
__device__ __forceinline__ unsigned pkbf(float a, float b) {
    union { float f; unsigned u; } x, y; x.f = a; y.f = b;
    return __builtin_amdgcn_perm(y.u, x.u, 0x07060302u);
}

// ---------------------------------------------------------------------------
// x (fp32) -> bf16
// ---------------------------------------------------------------------------
__global__ __launch_bounds__(256) void convert_bf16(
    const float* __restrict__ in, unsigned short* __restrict__ out, int n4)
{
    for (int i = blockIdx.x * blockDim.x + threadIdx.x; i < n4;
         i += gridDim.x * blockDim.x) {
        float4 v = *(const float4*)(in + (size_t)i * 4);
        ushort4 u;
        u.x = f2bf(v.x); u.y = f2bf(v.y); u.z = f2bf(v.z); u.w = f2bf(v.w);
        *(ushort4*)(out + (size_t)i * 4) = u;
    }
}

// ---------------------------------------------------------------------------
// All three weight transposes in one launch. fp32 [K][N] -> bf16 [N][K].
// ---------------------------------------------------------------------------
__global__ __launch_bounds__(256) void prep_w(
    const float* __restrict__ Wq, const float* __restrict__ Wkv,
    const float* __restrict__ Wo,
    unsigned short* __restrict__ Wqt, unsigned short* __restrict__ Wkvt,
    unsigned short* __restrict__ Wot)
{
    __shared__ float t[32][33];
    const int z = blockIdx.z;
    const float* W;  unsigned short* Wt;  int N, nc;
    if (z == 0)      { W = Wq;  Wt = Wqt;  N = 1024; nc = 0; }
    else if (z == 1) { W = Wo;  Wt = Wot;  N = 1024; nc = 0; }
    else             { W = Wkv; Wt = Wkvt; N = 2048; nc = (z - 2) * 1024; }
    const int tx = threadIdx.x & 31, ty = threadIdx.x >> 5;
    const int n0 = nc + blockIdx.x * 32, k0 = blockIdx.y * 32;
    #pragma unroll
    for (int r = 0; r < 4; ++r)
        t[ty + r * 8][tx] = W[(size_t)(k0 + ty + r * 8) * N + n0 + tx];
    __syncthreads();
    #pragma unroll
    for (int r = 0; r < 4; ++r)
        Wt[(size_t)(n0 + ty + r * 8) * 1024 + k0 + tx] = f2bf(t[tx][ty + r * 8]);
}

// ---------------------------------------------------------------------------
// Fused QKV projection, 256x256 tile, 8-phase pipelined schedule (T2+T3+T4+T5).
// Q (scaled) -> Qb, K -> dense Kb, V -> Vtg transposed. (unchanged)
// ---------------------------------------------------------------------------
__global__ __launch_bounds__(512, 1) void gemm_qkv8(
    const unsigned short* __restrict__ A,    // xb [4096][1024]
    const unsigned short* __restrict__ Bt,   // Wqkvt [3072][1024]
    const float* __restrict__ bq, const float* __restrict__ bkv,
    unsigned short* __restrict__ Qb, unsigned short* __restrict__ Kb,
    unsigned short* __restrict__ Vtg, float qscl)
{
    const int KDIM = 1024, NT = 16;  // K-tiles of 64
    __shared__ __align__(16) unsigned short lds[65536];  // 128 KiB

    const int tid = threadIdx.x;
    const int w = tid >> 6, l = tid & 63, g = l >> 4, ln = l & 15;
    const int wm = (w >> 2) & 1, wn = w & 3;

    const int lin = blockIdx.x;
    const int wg = (lin & 7) * 24 + (lin >> 3);
    const int by = wg / 12, bx = wg % 12;
    const int m0 = by * 256, n0 = bx * 256;

    const int sr8 = w * 8 + (l >> 3);
    const int sc  = (l & 7) ^ ((l >> 3) & 7);
    const unsigned short* Asrc = A  + (size_t)m0 * KDIM + sc * 8;
    const unsigned short* Bsrc = Bt + (size_t)n0 * KDIM + sc * 8;

#define SLOT_A(d, h) (lds + ((d) * 2 + (h)) * 8192)
#define SLOT_B(d, h) (lds + 32768 + ((d) * 2 + (h)) * 8192)

#define STG(slotp, srcp, hh, kt_) do {                                        \
    _Pragma("unroll")                                                         \
    for (int r_ = 0; r_ < 2; ++r_) {                                          \
        const int row_ = (hh) * 128 + r_ * 64 + sr8;                          \
        __builtin_amdgcn_global_load_lds(                                     \
            (const __attribute__((address_space(1))) void*)                   \
                ((srcp) + (size_t)row_ * KDIM + (kt_) * 64),                  \
            (__attribute__((address_space(3))) void*)                         \
                ((slotp) + r_ * 4096 + w * 512 + l * 8),                      \
            16, 0, 0);                                                        \
    }                                                                         \
} while (0)

    f32x4 acc[8][4];
    #pragma unroll
    for (int i = 0; i < 8; ++i)
        #pragma unroll
        for (int j = 0; j < 4; ++j) acc[i][j] = (f32x4){0.f, 0.f, 0.f, 0.f};

    bf16x8 aR[4][2], bB0[2][2], bB1[2][2];

    STG(SLOT_A(0, 0), Asrc, 0, 0);
    STG(SLOT_B(0, 1), Bsrc, 1, 0);
    STG(SLOT_A(0, 1), Asrc, 1, 0);
    STG(SLOT_B(0, 0), Bsrc, 0, 0);
    STG(SLOT_A(1, 0), Asrc, 0, 1);
    STG(SLOT_B(1, 1), Bsrc, 1, 1);

    #pragma unroll 1
    for (int kt = 0; kt < NT; ++kt) {
        const int cur = kt & 1, nxt = cur ^ 1;
        asm volatile("s_waitcnt vmcnt(4)" ::: "memory");
        __builtin_amdgcn_s_barrier();

        // ---- phase A ----
        #pragma unroll
        for (int mi = 0; mi < 4; ++mi)
            #pragma unroll
            for (int kc = 0; kc < 2; ++kc) {
                const int rho = wm * 64 + mi * 16 + ln, c = kc * 4 + g;
                aR[mi][kc] = *(const bf16x8*)
                    (SLOT_A(cur, 0) + rho * 64 + ((c ^ (rho & 7)) * 8));
            }
        #pragma unroll
        for (int ni = 0; ni < 2; ++ni)
            #pragma unroll
            for (int kc = 0; kc < 2; ++kc) {
                const int rho = wn * 32 + ni * 16 + ln, c = kc * 4 + g;
                bB0[ni][kc] = *(const bf16x8*)
                    (SLOT_B(cur, 0) + rho * 64 + ((c ^ (rho & 7)) * 8));
            }
        if (kt + 1 < NT) STG(SLOT_A(nxt, 1), Asrc, 1, kt + 1);
        __builtin_amdgcn_s_barrier();
        asm volatile("s_waitcnt lgkmcnt(0)" ::: "memory");
        __builtin_amdgcn_s_setprio(1);
        #pragma unroll
        for (int mi = 0; mi < 4; ++mi)
            #pragma unroll
            for (int ni = 0; ni < 2; ++ni) {
                acc[mi][ni] = MFMA16(aR[mi][0], bB0[ni][0], acc[mi][ni]);
                acc[mi][ni] = MFMA16(aR[mi][1], bB0[ni][1], acc[mi][ni]);
            }
        __builtin_amdgcn_s_setprio(0);
        __builtin_amdgcn_s_barrier();

        // ---- phase B ----
        #pragma unroll
        for (int ni = 0; ni < 2; ++ni)
            #pragma unroll
            for (int kc = 0; kc < 2; ++kc) {
                const int rho = wn * 32 + ni * 16 + ln, c = kc * 4 + g;
                bB1[ni][kc] = *(const bf16x8*)
                    (SLOT_B(cur, 1) + rho * 64 + ((c ^ (rho & 7)) * 8));
            }
        if (kt + 1 < NT) STG(SLOT_B(nxt, 0), Bsrc, 0, kt + 1);
        __builtin_amdgcn_s_barrier();
        asm volatile("s_waitcnt lgkmcnt(0)" ::: "memory");
        __builtin_amdgcn_s_setprio(1);
        #pragma unroll
        for (int mi = 0; mi < 4; ++mi)
            #pragma unroll
            for (int ni = 0; ni < 2; ++ni) {
                acc[mi][2 + ni] = MFMA16(aR[mi][0], bB1[ni][0], acc[mi][2 + ni]);
                acc[mi][2 + ni] = MFMA16(aR[mi][1], bB1[ni][1], acc[mi][2 + ni]);
            }
        __builtin_amdgcn_s_setprio(0);
        __builtin_amdgcn_s_barrier();

        // ---- phase C ----
        #pragma unroll
        for (int mi = 0; mi < 4; ++mi)
            #pragma unroll
            for (int kc = 0; kc < 2; ++kc) {
                const int rho = wm * 64 + mi * 16 + ln, c = kc * 4 + g;
                aR[mi][kc] = *(const bf16x8*)
                    (SLOT_A(cur, 1) + rho * 64 + ((c ^ (rho & 7)) * 8));
            }
        if (kt + 2 < NT) STG(SLOT_A(cur, 0), Asrc, 0, kt + 2);
        __builtin_amdgcn_s_barrier();
        asm volatile("s_waitcnt lgkmcnt(0)" ::: "memory");
        __builtin_amdgcn_s_setprio(1);
        #pragma unroll
        for (int mi = 0; mi < 4; ++mi)
            #pragma unroll
            for (int ni = 0; ni < 2; ++ni) {
                acc[4 + mi][2 + ni] = MFMA16(aR[mi][0], bB1[ni][0], acc[4 + mi][2 + ni]);
                acc[4 + mi][2 + ni] = MFMA16(aR[mi][1], bB1[ni][1], acc[4 + mi][2 + ni]);
            }
        __builtin_amdgcn_s_setprio(0);
        __builtin_amdgcn_s_barrier();

        // ---- phase D ----
        if (kt + 2 < NT) STG(SLOT_B(cur, 1), Bsrc, 1, kt + 2);
        __builtin_amdgcn_s_barrier();
        __builtin_amdgcn_s_setprio(1);
        #pragma unroll
        for (int mi = 0; mi < 4; ++mi)
            #pragma unroll
            for (int ni = 0; ni < 2; ++ni) {
                acc[4 + mi][ni] = MFMA16(aR[mi][0], bB0[ni][0], acc[4 + mi][ni]);
                acc[4 + mi][ni] = MFMA16(aR[mi][1], bB0[ni][1], acc[4 + mi][ni]);
            }
        __builtin_amdgcn_s_setprio(0);
        __builtin_amdgcn_s_barrier();
    }
#undef STG
#undef SLOT_A
#undef SLOT_B

    const int region = n0 >> 10;  // 0=Q, 1=K, 2=V
    if (region == 2) {
        #pragma unroll
        for (int nh = 0; nh < 2; ++nh)
            #pragma unroll
            for (int ni = 0; ni < 2; ++ni) {
                const int d = n0 - 2048 + nh * 128 + wn * 32 + ni * 16 + ln;
                const float bv = bkv[1024 + d];
                #pragma unroll
                for (int mh = 0; mh < 2; ++mh)
                    #pragma unroll
                    for (int mi = 0; mi < 4; ++mi) {
                        const int tok = m0 + mh * 128 + wm * 64 + mi * 16 + g * 4;
                        const int bb = tok >> 11, t4 = tok & 2047;
                        const f32x4 av = acc[mh * 4 + mi][nh * 2 + ni];
                        ushort4 p4;
                        p4.x = f2bf(av[0] + bv); p4.y = f2bf(av[1] + bv);
                        p4.z = f2bf(av[2] + bv); p4.w = f2bf(av[3] + bv);
                        *(ushort4*)(Vtg + ((size_t)bb * 1024 + d) * 2048 + t4) = p4;
                    }
            }
    } else {
        const int isQ = (region == 0);
        const float osc = isQ ? qscl : 1.f;
        #pragma unroll
        for (int nh = 0; nh < 2; ++nh)
            #pragma unroll
            for (int ni = 0; ni < 2; ++ni) {
                const int col = n0 + nh * 128 + wn * 32 + ni * 16 + ln;
                const float bv = isQ ? bq[col] : bkv[col - 1024];
                const int ck = isQ ? col : col - 1024;
                #pragma unroll
                for (int mh = 0; mh < 2; ++mh)
                    #pragma unroll
                    for (int mi = 0; mi < 4; ++mi) {
                        const int row = m0 + mh * 128 + wm * 64 + mi * 16 + g * 4;
                        const f32x4 av = acc[mh * 4 + mi][nh * 2 + ni];
                        #pragma unroll
                        for (int r = 0; r < 4; ++r) {
                            const float vout = (av[r] + bv) * osc;
                            if (isQ)
                                Qb[(size_t)(row + r) * 1024 + ck] = f2bf(vout);
                            else
                                Kb[(size_t)(row + r) * 1024 + ck] = f2bf(vout);
                        }
                    }
            }
    }
}

// ---------------------------------------------------------------------------
// bf16 MFMA GEMM (out-projection): C[M,N] = A[M,K] @ Bt[N,K]^T + bias (fp32)
// ---------------------------------------------------------------------------
__global__ __launch_bounds__(256) void gemm_bt(
    const unsigned short* __restrict__ A,
    const unsigned short* __restrict__ Bt,
    const float* __restrict__ bias,
    float* __restrict__ Cout, int M, int N, int K)
{
    __shared__ __align__(16) unsigned short As[128 * 32];
    __shared__ __align__(16) unsigned short Bs[128 * 32];
    const int tid = threadIdx.x;
    const int w = tid >> 6, l = tid & 63, g = l >> 4, ln = l & 15;
    const int wm = w >> 1, wn = w & 1;
    const int m0 = blockIdx.y * 128, n0 = blockIdx.x * 128;

    f32x4 acc[4][4];
    #pragma unroll
    for (int i = 0; i < 4; ++i)
        #pragma unroll
        for (int j = 0; j < 4; ++j) acc[i][j] = (f32x4){0.f, 0.f, 0.f, 0.f};

    const char* Ab = (const char*)A;
    const char* Bb = (const char*)Bt;
    const size_t strideK = (size_t)K * 2;

    for (int k0 = 0; k0 < K; k0 += 32) {
        #pragma unroll
        for (int i = 0; i < 2; ++i) {
            const int b = w * 2048 + i * 1024 + l * 16;
            const int row = b >> 6, cb = b & 63;
            __builtin_amdgcn_global_load_lds(
                (const __attribute__((address_space(1))) void*)
                    (Ab + (size_t)(m0 + row) * strideK + (size_t)k0 * 2 + cb),
                (__attribute__((address_space(3))) void*)
                    ((char*)As + w * 2048 + i * 1024),
                16, 0, 0);
            __builtin_amdgcn_global_load_lds(
                (const __attribute__((address_space(1))) void*)
                    (Bb + (size_t)(n0 + row) * strideK + (size_t)k0 * 2 + cb),
                (__attribute__((address_space(3))) void*)
                    ((char*)Bs + w * 2048 + i * 1024),
                16, 0, 0);
        }
        __syncthreads();
        bf16x8 af[4], bfr[4];
        #pragma unroll
        for (int m = 0; m < 4; ++m)
            af[m] = *(const bf16x8*)(As + (wm * 64 + m * 16 + ln) * 32 + g * 8);
        #pragma unroll
        for (int n = 0; n < 4; ++n)
            bfr[n] = *(const bf16x8*)(Bs + (wn * 64 + n * 16 + ln) * 32 + g * 8);
        #pragma unroll
        for (int m = 0; m < 4; ++m)
            #pragma unroll
            for (int n = 0; n < 4; ++n)
                acc[m][n] = MFMA16(af[m], bfr[n], acc[m][n]);
        __syncthreads();
    }

    #pragma unroll
    for (int n = 0; n < 4; ++n) {
        const int col = n0 + wn * 64 + n * 16 + ln;
        const float bv = bias[col];
        #pragma unroll
        for (int m = 0; m < 4; ++m) {
            const int row = m0 + wm * 64 + m * 16 + g * 4;
            #pragma unroll
            for (int r = 0; r < 4; ++r)
                Cout[(size_t)(row + r) * N + col] = acc[m][n][r] + bv;
        }
    }
}

// ---------------------------------------------------------------------------
// bf16 MFMA flash attention v7 = v6b + split-K (2 halves).
// Grid 1024: each block owns (b, h, qc, khalf) and iterates keys
// [khalf*1024, khalf*1024+1024) in 16 KVBLK=64 bodies. Occupancy doubles
// (4096 waves = 4/SIMD) -- the kernel is VALU/exp2-limited and latency-
// exposed at 2 waves/SIMD. No-max softmax makes partials additive:
// O = O0+O1, l = l0+l1, accumulated via f32 atomicAdd into Of/Lf (exactly
// 2 contributions per address -> 2-operand fadd commutes -> deterministic).
// Per-body math identical to v6b (verified).
// ---------------------------------------------------------------------------
__global__ __launch_bounds__(256) void attn_mfma(
    const unsigned short* __restrict__ Qb,
    const unsigned short* __restrict__ Kb,
    const unsigned short* __restrict__ Vtg,
    float* __restrict__ Of, float* __restrict__ Lf)
{
    __shared__ __align__(16) unsigned short Ks[2][64 * 64];
    __shared__ __align__(16) unsigned short Vs[2][64 * 64];

    const int tid = threadIdx.x;
    const int w = tid >> 6, l = tid & 63;
    const int l31 = l & 31, hi = l >> 5, l7 = l & 7;
    const int dd = blockIdx.x;
    const int bid = (dd & 7) * 128 + (dd >> 3);  // T1 XCD remap (1024%8==0)
    const int kh = bid & 1, qc = (bid >> 1) & 15;
    const int h = (bid >> 5) & 15, b = bid >> 9;
    const int qrow = b * L_ + qc * 128 + w * 32;
    const int kbase = kh * 16;                   // first KV tile (of 64 keys)

    const int sub = l >> 3;
    const int scc = (l & 7) ^ sub;               // pre-swizzled source chunk
    const unsigned short* ksrc = Kb  + (size_t)(b * L_) * 1024 + h * HD_ + scc * 8;
    const unsigned short* vsrc = Vtg + (size_t)(b * D_ + h * HD_) * 2048 + scc * 8;

#define STAGE(jj, bb) do {                                                    \
    _Pragma("unroll")                                                         \
    for (int i_ = 0; i_ < 2; ++i_) {                                          \
        const int rowK = w * 16 + i_ * 8 + sub;                               \
        __builtin_amdgcn_global_load_lds(                                     \
            (const __attribute__((address_space(1))) void*)                   \
                (ksrc + (size_t)((jj) * 64 + rowK) * 1024),                   \
            (__attribute__((address_space(3))) void*)                         \
                (&Ks[bb][w * 1024 + i_ * 512]), 16, 0, 0);                    \
        __builtin_amdgcn_global_load_lds(                                     \
            (const __attribute__((address_space(1))) void*)                   \
                (vsrc + (size_t)rowK * 2048 + (jj) * 64),                     \
            (__attribute__((address_space(3))) void*)                         \
                (&Vs[bb][w * 1024 + i_ * 512]), 16, 0, 0);                    \
    }                                                                         \
} while (0)

    // Q fragments (B-operand, 32x32x16): col q = l31, k = dh*16 + hi*8 + j.
    bf16x8 qa[4];
    #pragma unroll
    for (int dh = 0; dh < 4; ++dh)
        qa[dh] = *(const bf16x8*)
            (Qb + (size_t)(qrow + l31) * D_ + h * HD_ + dh * 16 + hi * 8);

    const f32x16 z16 = {0.f,0.f,0.f,0.f,0.f,0.f,0.f,0.f,
                        0.f,0.f,0.f,0.f,0.f,0.f,0.f,0.f};
    f32x16 o2[2], lacc;
    o2[0] = z16; o2[1] = z16; lacc = z16;

    const short one_s = (short)0x3F80;  // bf16 1.0
    const bf16x8 ones = {one_s, one_s, one_s, one_s, one_s, one_s, one_s, one_s};

#define ATT_BODY(BUF, TNEXT, NBUF, DOSTG) do {                                \
    if (DOSTG) STAGE(TNEXT, NBUF);                                            \
    const unsigned short* Kc = &Ks[BUF][0];                                   \
    const unsigned short* Vc = &Vs[BUF][0];                                   \
    bf16x8 kbf[2][4];                                                         \
    _Pragma("unroll")                                                         \
    for (int kk = 0; kk < 2; ++kk)                                            \
        _Pragma("unroll")                                                     \
        for (int dh = 0; dh < 4; ++dh)                                        \
            kbf[kk][dh] = *(const bf16x8*)                                    \
                (Kc + (kk * 32 + l31) * 64 + (((2 * dh + hi) ^ l7) * 8));     \
    f32x16 s2[2];                                                             \
    __builtin_amdgcn_s_setprio(1);                                            \
    _Pragma("unroll")                                                         \
    for (int kk = 0; kk < 2; ++kk) {                                          \
        s2[kk] = MFMA32(kbf[kk][0], qa[0], z16);                              \
        s2[kk] = MFMA32(kbf[kk][1], qa[1], s2[kk]);                           \
        s2[kk] = MFMA32(kbf[kk][2], qa[2], s2[kk]);                           \
        s2[kk] = MFMA32(kbf[kk][3], qa[3], s2[kk]);                           \
    }                                                                         \
    __builtin_amdgcn_s_setprio(0);                                            \
    _Pragma("unroll")                                                         \
    for (int kk = 0; kk < 2; ++kk)                                            \
        _Pragma("unroll")                                                     \
        for (int r = 0; r < 16; ++r)                                          \
            s2[kk][r] = __builtin_exp2f(s2[kk][r]);                           \
    bf16x8 pa[4];                                                             \
    _Pragma("unroll")                                                         \
    for (int ks = 0; ks < 4; ++ks) {                                          \
        const int kk = ks >> 1, R = 8 * (ks & 1);                             \
        unsigned d0 = pkbf(s2[kk][R + 0], s2[kk][R + 1]);                     \
        unsigned d1 = pkbf(s2[kk][R + 2], s2[kk][R + 3]);                     \
        unsigned d2 = pkbf(s2[kk][R + 4], s2[kk][R + 5]);                     \
        unsigned d3 = pkbf(s2[kk][R + 6], s2[kk][R + 7]);                     \
        asm volatile("v_permlane32_swap_b32 %0, %1" : "+v"(d0), "+v"(d2));    \
        asm volatile("v_permlane32_swap_b32 %0, %1" : "+v"(d1), "+v"(d3));    \
        union { unsigned u[4]; bf16x8 v; } pk_;                               \
        pk_.u[0] = d0; pk_.u[1] = d1; pk_.u[2] = d2; pk_.u[3] = d3;           \
        pa[ks] = pk_.v;                                                       \
    }                                                                         \
    bf16x8 vbf[2][4];                                                         \
    _Pragma("unroll")                                                         \
    for (int dt = 0; dt < 2; ++dt)                                            \
        _Pragma("unroll")                                                     \
        for (int ks = 0; ks < 4; ++ks)                                        \
            vbf[dt][ks] = *(const bf16x8*)                                    \
                (Vc + (dt * 32 + l31) * 64 + (((2 * ks + hi) ^ l7) * 8));     \
    __builtin_amdgcn_s_setprio(1);                                            \
    _Pragma("unroll")                                                         \
    for (int dt = 0; dt < 2; ++dt)                                            \
        _Pragma("unroll")                                                     \
        for (int ks = 0; ks < 4; ++ks)                                        \
            o2[dt] = MFMA32(pa[ks], vbf[dt][ks], o2[dt]);                     \
    _Pragma("unroll")                                                         \
    for (int ks = 0; ks < 4; ++ks)                                            \
        lacc = MFMA32(pa[ks], ones, lacc);                                    \
    __builtin_amdgcn_s_setprio(0);                                            \
} while (0)

    STAGE(kbase, 0);
    __syncthreads();

    #pragma unroll 1
    for (int t = 0; t < 16; t += 2) {
        ATT_BODY(0, kbase + t + 1, 1, true);
        __syncthreads();
        ATT_BODY(1, kbase + t + 2, 0, (t + 2 < 16));
        __syncthreads();
    }
#undef ATT_BODY
#undef STAGE

    // accumulate partials: O rows q = qrow + (r&3)+8*(r>>2)+4*hi, col dt*32+l31
    #pragma unroll
    for (int r = 0; r < 16; ++r) {
        const int row = qrow + (r & 3) + 8 * (r >> 2) + 4 * hi;
        #pragma unroll
        for (int dt = 0; dt < 2; ++dt)
            atomicAdd(&Of[(size_t)row * D_ + h * HD_ + dt * 32 + l31], o2[dt][r]);
        if (l31 == 0)
            atomicAdd(&Lf[row * H_ + h], lacc[r]);
    }
}

// ---------------------------------------------------------------------------
// combine: Yb[row][col] = bf16(Of[row][col] / Lf[row][col>>6])
// ---------------------------------------------------------------------------
__global__ __launch_bounds__(256) void combine(
    const float* __restrict__ Of, const float* __restrict__ Lf,
    unsigned short* __restrict__ Yb)
{
    const int i = blockIdx.x * blockDim.x + threadIdx.x;  // per 4 elems
    const int idx = i * 4;
    const int row = idx >> 10, col = idx & 1023;
    const float inv = 1.f / Lf[row * H_ + (col >> 6)];
    float4 o = *(const float4*)(Of + idx);
    ushort4 y;
    y.x = f2bf(o.x * inv); y.y = f2bf(o.y * inv);
    y.z = f2bf(o.z * inv); y.w = f2bf(o.w * inv);
    *(ushort4*)(Yb + idx) = y;
}

// ---------------------------------------------------------------------------
extern "C" void kernel_launch(void* const* d_in, const int* in_sizes, int n_in,
                              void* d_out, int out_size, void* d_ws, size_t ws_size,
                              hipStream_t stream)
{
    const float* x   = (const float*)d_in[0];
    const float* Wq  = (const float*)d_in[1];
    const float* bq  = (const float*)d_in[2];
    const float* Wkv = (const float*)d_in[3];
    const float* bkv = (const float*)d_in[4];
    const float* Wo  = (const float*)d_in[5];
    const float* bo  = (const float*)d_in[6];
    float* out = (float*)d_out;

    const int M = B_ * L_;  // 4096
    unsigned short* ws = (unsigned short*)d_ws;
    unsigned short* xb   = ws;                          // 8MB (also reused as Yb)
    unsigned short* Wqt  = xb   + (size_t)M * D_;       // 2MB \ adjacent =
    unsigned short* Wkvt = Wqt  + (size_t)D_ * D_;      // 4MB / Bt[3072][1024]
    unsigned short* Wot  = Wkvt + (size_t)2 * D_ * D_;  // 2MB
    unsigned short* Qb   = Wot  + (size_t)D_ * D_;      // 8MB
    unsigned short* Kb   = Qb   + (size_t)M * D_;       // 8MB
    unsigned short* Vtg  = Kb   + (size_t)M * D_;       // 8MB
    float* Of = (float*)(Vtg + (size_t)B_ * D_ * L_);   // 16MB
    float* Lf = Of + (size_t)M * D_;                    // 256KB (total ~56.3MB)
    unsigned short* Yb = xb;  // xb dead after gemm_qkv8; combine writes here

    const float QSCL = 0.125f * 1.44269504089f;  // 1/sqrt(HD) * log2(e)

    // prep: x -> bf16; all weight transposes in one launch
    convert_bf16<<<2048, 256, 0, stream>>>(x, xb, M * D_ / 4);
    prep_w<<<dim3(32, 32, 4), 256, 0, stream>>>(Wq, Wkv, Wo, Wqt, Wkvt, Wot);

    // fused QKV projection, 256^2 8-phase (192 blocks); V written transposed
    gemm_qkv8<<<dim3(192), 512, 0, stream>>>(xb, Wqt, bq, bkv, Qb, Kb, Vtg, QSCL);

    // zero the split-K accumulators (graph-safe async memset)
    hipMemsetAsync(Of, 0, (size_t)M * D_ * 4, stream);
    hipMemsetAsync(Lf, 0, (size_t)M * H_ * 4, stream);

    // flash attention, split-K=2 -> Of/Lf partial sums (1024 blocks)
    attn_mfma<<<dim3(B_ * H_ * (L_ / 128) * 2), 256, 0, stream>>>(
        Qb, Kb, Vtg, Of, Lf);

    // combine -> Yb bf16 [M][D]
    combine<<<dim3(M * D_ / 4 / 256), 256, 0, stream>>>(Of, Lf, Yb);

    // out = Yb@Wo + bo (fp32 out)
    gemm_bt<<<dim3(D_ / 128, M / 128), 256, 0, stream>>>(Yb, Wot, bo, out, M, D_, D_);
}

// Round 11
// 140.787 us; speedup vs baseline: 1.2329x; 1.2329x over previous
//
#include <hip/hip_runtime.h>

#define B_  2
#define L_  2048
#define D_  1024
#define H_  16
#define HD_ 64

typedef __attribute__((ext_vector_type(8))) short bf16x8;
typedef __attribute__((ext_vector_type(4))) float f32x4;
typedef __attribute__((ext_vector_type(16))) float f32x16;

#define MFMA16(a, b, c) __builtin_amdgcn_mfma_f32_16x16x32_bf16(a, b, c, 0, 0, 0)
#define MFMA32(a, b, c) __builtin_amdgcn_mfma_f32_32x32x16_bf16(a, b, c, 0, 0, 0)

__device__ __forceinline__ unsigned short f2bf(float f) {
    union { float f; unsigned u; } v; v.f = f;
    unsigned r = v.u + 0x7FFFu + ((v.u >> 16) & 1u);
    return (unsigned short)(r >> 16);
}

// pack two f32 -> one dword of 2 bf16 (truncation); elem0 (low16) = a
__device__ __forceinline__ unsigned pkbf(float a, float b) {
    union { float f; unsigned u; } x, y; x.f = a; y.f = b;
    return __builtin_amdgcn_perm(y.u, x.u, 0x07060302u);
}

// ---------------------------------------------------------------------------
// x (fp32) -> bf16
// ---------------------------------------------------------------------------
__global__ __launch_bounds__(256) void convert_bf16(
    const float* __restrict__ in, unsigned short* __restrict__ out, int n4)
{
    for (int i = blockIdx.x * blockDim.x + threadIdx.x; i < n4;
         i += gridDim.x * blockDim.x) {
        float4 v = *(const float4*)(in + (size_t)i * 4);
        ushort4 u;
        u.x = f2bf(v.x); u.y = f2bf(v.y); u.z = f2bf(v.z); u.w = f2bf(v.w);
        *(ushort4*)(out + (size_t)i * 4) = u;
    }
}

// ---------------------------------------------------------------------------
// All three weight transposes in one launch. fp32 [K][N] -> bf16 [N][K].
// ---------------------------------------------------------------------------
__global__ __launch_bounds__(256) void prep_w(
    const float* __restrict__ Wq, const float* __restrict__ Wkv,
    const float* __restrict__ Wo,
    unsigned short* __restrict__ Wqt, unsigned short* __restrict__ Wkvt,
    unsigned short* __restrict__ Wot)
{
    __shared__ float t[32][33];
    const int z = blockIdx.z;
    const float* W;  unsigned short* Wt;  int N, nc;
    if (z == 0)      { W = Wq;  Wt = Wqt;  N = 1024; nc = 0; }
    else if (z == 1) { W = Wo;  Wt = Wot;  N = 1024; nc = 0; }
    else             { W = Wkv; Wt = Wkvt; N = 2048; nc = (z - 2) * 1024; }
    const int tx = threadIdx.x & 31, ty = threadIdx.x >> 5;
    const int n0 = nc + blockIdx.x * 32, k0 = blockIdx.y * 32;
    #pragma unroll
    for (int r = 0; r < 4; ++r)
        t[ty + r * 8][tx] = W[(size_t)(k0 + ty + r * 8) * N + n0 + tx];
    __syncthreads();
    #pragma unroll
    for (int r = 0; r < 4; ++r)
        Wt[(size_t)(n0 + ty + r * 8) * 1024 + k0 + tx] = f2bf(t[tx][ty + r * 8]);
}

// ---------------------------------------------------------------------------
// Fused QKV projection, 256x256 tile, 8-phase pipelined schedule (T2+T3+T4+T5).
// Q (scaled) -> Qb, K -> dense Kb, V -> Vtg transposed. (unchanged)
// ---------------------------------------------------------------------------
__global__ __launch_bounds__(512, 1) void gemm_qkv8(
    const unsigned short* __restrict__ A,    // xb [4096][1024]
    const unsigned short* __restrict__ Bt,   // Wqkvt [3072][1024]
    const float* __restrict__ bq, const float* __restrict__ bkv,
    unsigned short* __restrict__ Qb, unsigned short* __restrict__ Kb,
    unsigned short* __restrict__ Vtg, float qscl)
{
    const int KDIM = 1024, NT = 16;  // K-tiles of 64
    __shared__ __align__(16) unsigned short lds[65536];  // 128 KiB

    const int tid = threadIdx.x;
    const int w = tid >> 6, l = tid & 63, g = l >> 4, ln = l & 15;
    const int wm = (w >> 2) & 1, wn = w & 3;

    const int lin = blockIdx.x;
    const int wg = (lin & 7) * 24 + (lin >> 3);
    const int by = wg / 12, bx = wg % 12;
    const int m0 = by * 256, n0 = bx * 256;

    const int sr8 = w * 8 + (l >> 3);
    const int sc  = (l & 7) ^ ((l >> 3) & 7);
    const unsigned short* Asrc = A  + (size_t)m0 * KDIM + sc * 8;
    const unsigned short* Bsrc = Bt + (size_t)n0 * KDIM + sc * 8;

#define SLOT_A(d, h) (lds + ((d) * 2 + (h)) * 8192)
#define SLOT_B(d, h) (lds + 32768 + ((d) * 2 + (h)) * 8192)

#define STG(slotp, srcp, hh, kt_) do {                                        \
    _Pragma("unroll")                                                         \
    for (int r_ = 0; r_ < 2; ++r_) {                                          \
        const int row_ = (hh) * 128 + r_ * 64 + sr8;                          \
        __builtin_amdgcn_global_load_lds(                                     \
            (const __attribute__((address_space(1))) void*)                   \
                ((srcp) + (size_t)row_ * KDIM + (kt_) * 64),                  \
            (__attribute__((address_space(3))) void*)                         \
                ((slotp) + r_ * 4096 + w * 512 + l * 8),                      \
            16, 0, 0);                                                        \
    }                                                                         \
} while (0)

    f32x4 acc[8][4];
    #pragma unroll
    for (int i = 0; i < 8; ++i)
        #pragma unroll
        for (int j = 0; j < 4; ++j) acc[i][j] = (f32x4){0.f, 0.f, 0.f, 0.f};

    bf16x8 aR[4][2], bB0[2][2], bB1[2][2];

    STG(SLOT_A(0, 0), Asrc, 0, 0);
    STG(SLOT_B(0, 1), Bsrc, 1, 0);
    STG(SLOT_A(0, 1), Asrc, 1, 0);
    STG(SLOT_B(0, 0), Bsrc, 0, 0);
    STG(SLOT_A(1, 0), Asrc, 0, 1);
    STG(SLOT_B(1, 1), Bsrc, 1, 1);

    #pragma unroll 1
    for (int kt = 0; kt < NT; ++kt) {
        const int cur = kt & 1, nxt = cur ^ 1;
        asm volatile("s_waitcnt vmcnt(4)" ::: "memory");
        __builtin_amdgcn_s_barrier();

        // ---- phase A ----
        #pragma unroll
        for (int mi = 0; mi < 4; ++mi)
            #pragma unroll
            for (int kc = 0; kc < 2; ++kc) {
                const int rho = wm * 64 + mi * 16 + ln, c = kc * 4 + g;
                aR[mi][kc] = *(const bf16x8*)
                    (SLOT_A(cur, 0) + rho * 64 + ((c ^ (rho & 7)) * 8));
            }
        #pragma unroll
        for (int ni = 0; ni < 2; ++ni)
            #pragma unroll
            for (int kc = 0; kc < 2; ++kc) {
                const int rho = wn * 32 + ni * 16 + ln, c = kc * 4 + g;
                bB0[ni][kc] = *(const bf16x8*)
                    (SLOT_B(cur, 0) + rho * 64 + ((c ^ (rho & 7)) * 8));
            }
        if (kt + 1 < NT) STG(SLOT_A(nxt, 1), Asrc, 1, kt + 1);
        __builtin_amdgcn_s_barrier();
        asm volatile("s_waitcnt lgkmcnt(0)" ::: "memory");
        __builtin_amdgcn_s_setprio(1);
        #pragma unroll
        for (int mi = 0; mi < 4; ++mi)
            #pragma unroll
            for (int ni = 0; ni < 2; ++ni) {
                acc[mi][ni] = MFMA16(aR[mi][0], bB0[ni][0], acc[mi][ni]);
                acc[mi][ni] = MFMA16(aR[mi][1], bB0[ni][1], acc[mi][ni]);
            }
        __builtin_amdgcn_s_setprio(0);
        __builtin_amdgcn_s_barrier();

        // ---- phase B ----
        #pragma unroll
        for (int ni = 0; ni < 2; ++ni)
            #pragma unroll
            for (int kc = 0; kc < 2; ++kc) {
                const int rho = wn * 32 + ni * 16 + ln, c = kc * 4 + g;
                bB1[ni][kc] = *(const bf16x8*)
                    (SLOT_B(cur, 1) + rho * 64 + ((c ^ (rho & 7)) * 8));
            }
        if (kt + 1 < NT) STG(SLOT_B(nxt, 0), Bsrc, 0, kt + 1);
        __builtin_amdgcn_s_barrier();
        asm volatile("s_waitcnt lgkmcnt(0)" ::: "memory");
        __builtin_amdgcn_s_setprio(1);
        #pragma unroll
        for (int mi = 0; mi < 4; ++mi)
            #pragma unroll
            for (int ni = 0; ni < 2; ++ni) {
                acc[mi][2 + ni] = MFMA16(aR[mi][0], bB1[ni][0], acc[mi][2 + ni]);
                acc[mi][2 + ni] = MFMA16(aR[mi][1], bB1[ni][1], acc[mi][2 + ni]);
            }
        __builtin_amdgcn_s_setprio(0);
        __builtin_amdgcn_s_barrier();

        // ---- phase C ----
        #pragma unroll
        for (int mi = 0; mi < 4; ++mi)
            #pragma unroll
            for (int kc = 0; kc < 2; ++kc) {
                const int rho = wm * 64 + mi * 16 + ln, c = kc * 4 + g;
                aR[mi][kc] = *(const bf16x8*)
                    (SLOT_A(cur, 1) + rho * 64 + ((c ^ (rho & 7)) * 8));
            }
        if (kt + 2 < NT) STG(SLOT_A(cur, 0), Asrc, 0, kt + 2);
        __builtin_amdgcn_s_barrier();
        asm volatile("s_waitcnt lgkmcnt(0)" ::: "memory");
        __builtin_amdgcn_s_setprio(1);
        #pragma unroll
        for (int mi = 0; mi < 4; ++mi)
            #pragma unroll
            for (int ni = 0; ni < 2; ++ni) {
                acc[4 + mi][2 + ni] = MFMA16(aR[mi][0], bB1[ni][0], acc[4 + mi][2 + ni]);
                acc[4 + mi][2 + ni] = MFMA16(aR[mi][1], bB1[ni][1], acc[4 + mi][2 + ni]);
            }
        __builtin_amdgcn_s_setprio(0);
        __builtin_amdgcn_s_barrier();

        // ---- phase D ----
        if (kt + 2 < NT) STG(SLOT_B(cur, 1), Bsrc, 1, kt + 2);
        __builtin_amdgcn_s_barrier();
        __builtin_amdgcn_s_setprio(1);
        #pragma unroll
        for (int mi = 0; mi < 4; ++mi)
            #pragma unroll
            for (int ni = 0; ni < 2; ++ni) {
                acc[4 + mi][ni] = MFMA16(aR[mi][0], bB0[ni][0], acc[4 + mi][ni]);
                acc[4 + mi][ni] = MFMA16(aR[mi][1], bB0[ni][1], acc[4 + mi][ni]);
            }
        __builtin_amdgcn_s_setprio(0);
        __builtin_amdgcn_s_barrier();
    }
#undef STG
#undef SLOT_A
#undef SLOT_B

    const int region = n0 >> 10;  // 0=Q, 1=K, 2=V
    if (region == 2) {
        #pragma unroll
        for (int nh = 0; nh < 2; ++nh)
            #pragma unroll
            for (int ni = 0; ni < 2; ++ni) {
                const int d = n0 - 2048 + nh * 128 + wn * 32 + ni * 16 + ln;
                const float bv = bkv[1024 + d];
                #pragma unroll
                for (int mh = 0; mh < 2; ++mh)
                    #pragma unroll
                    for (int mi = 0; mi < 4; ++mi) {
                        const int tok = m0 + mh * 128 + wm * 64 + mi * 16 + g * 4;
                        const int bb = tok >> 11, t4 = tok & 2047;
                        const f32x4 av = acc[mh * 4 + mi][nh * 2 + ni];
                        ushort4 p4;
                        p4.x = f2bf(av[0] + bv); p4.y = f2bf(av[1] + bv);
                        p4.z = f2bf(av[2] + bv); p4.w = f2bf(av[3] + bv);
                        *(ushort4*)(Vtg + ((size_t)bb * 1024 + d) * 2048 + t4) = p4;
                    }
            }
    } else {
        const int isQ = (region == 0);
        const float osc = isQ ? qscl : 1.f;
        #pragma unroll
        for (int nh = 0; nh < 2; ++nh)
            #pragma unroll
            for (int ni = 0; ni < 2; ++ni) {
                const int col = n0 + nh * 128 + wn * 32 + ni * 16 + ln;
                const float bv = isQ ? bq[col] : bkv[col - 1024];
                const int ck = isQ ? col : col - 1024;
                #pragma unroll
                for (int mh = 0; mh < 2; ++mh)
                    #pragma unroll
                    for (int mi = 0; mi < 4; ++mi) {
                        const int row = m0 + mh * 128 + wm * 64 + mi * 16 + g * 4;
                        const f32x4 av = acc[mh * 4 + mi][nh * 2 + ni];
                        #pragma unroll
                        for (int r = 0; r < 4; ++r) {
                            const float vout = (av[r] + bv) * osc;
                            if (isQ)
                                Qb[(size_t)(row + r) * 1024 + ck] = f2bf(vout);
                            else
                                Kb[(size_t)(row + r) * 1024 + ck] = f2bf(vout);
                        }
                    }
            }
    }
}

// ---------------------------------------------------------------------------
// bf16 MFMA GEMM (out-projection): C[M,N] = A[M,K] @ Bt[N,K]^T + bias (fp32)
// ---------------------------------------------------------------------------
__global__ __launch_bounds__(256) void gemm_bt(
    const unsigned short* __restrict__ A,
    const unsigned short* __restrict__ Bt,
    const float* __restrict__ bias,
    float* __restrict__ Cout, int M, int N, int K)
{
    __shared__ __align__(16) unsigned short As[128 * 32];
    __shared__ __align__(16) unsigned short Bs[128 * 32];
    const int tid = threadIdx.x;
    const int w = tid >> 6, l = tid & 63, g = l >> 4, ln = l & 15;
    const int wm = w >> 1, wn = w & 1;
    const int m0 = blockIdx.y * 128, n0 = blockIdx.x * 128;

    f32x4 acc[4][4];
    #pragma unroll
    for (int i = 0; i < 4; ++i)
        #pragma unroll
        for (int j = 0; j < 4; ++j) acc[i][j] = (f32x4){0.f, 0.f, 0.f, 0.f};

    const char* Ab = (const char*)A;
    const char* Bb = (const char*)Bt;
    const size_t strideK = (size_t)K * 2;

    for (int k0 = 0; k0 < K; k0 += 32) {
        #pragma unroll
        for (int i = 0; i < 2; ++i) {
            const int b = w * 2048 + i * 1024 + l * 16;
            const int row = b >> 6, cb = b & 63;
            __builtin_amdgcn_global_load_lds(
                (const __attribute__((address_space(1))) void*)
                    (Ab + (size_t)(m0 + row) * strideK + (size_t)k0 * 2 + cb),
                (__attribute__((address_space(3))) void*)
                    ((char*)As + w * 2048 + i * 1024),
                16, 0, 0);
            __builtin_amdgcn_global_load_lds(
                (const __attribute__((address_space(1))) void*)
                    (Bb + (size_t)(n0 + row) * strideK + (size_t)k0 * 2 + cb),
                (__attribute__((address_space(3))) void*)
                    ((char*)Bs + w * 2048 + i * 1024),
                16, 0, 0);
        }
        __syncthreads();
        bf16x8 af[4], bfr[4];
        #pragma unroll
        for (int m = 0; m < 4; ++m)
            af[m] = *(const bf16x8*)(As + (wm * 64 + m * 16 + ln) * 32 + g * 8);
        #pragma unroll
        for (int n = 0; n < 4; ++n)
            bfr[n] = *(const bf16x8*)(Bs + (wn * 64 + n * 16 + ln) * 32 + g * 8);
        #pragma unroll
        for (int m = 0; m < 4; ++m)
            #pragma unroll
            for (int n = 0; n < 4; ++n)
                acc[m][n] = MFMA16(af[m], bfr[n], acc[m][n]);
        __syncthreads();
    }

    #pragma unroll
    for (int n = 0; n < 4; ++n) {
        const int col = n0 + wn * 64 + n * 16 + ln;
        const float bv = bias[col];
        #pragma unroll
        for (int m = 0; m < 4; ++m) {
            const int row = m0 + wm * 64 + m * 16 + g * 4;
            #pragma unroll
            for (int r = 0; r < 4; ++r)
                Cout[(size_t)(row + r) * N + col] = acc[m][n][r] + bv;
        }
    }
}

// ---------------------------------------------------------------------------
// bf16 MFMA flash attention v8 = v6b + T4 counted-vmcnt pipeline.
// Structure change only: per body, {STAGE(t+1) issue -> s_waitcnt vmcnt(4)
// (STAGE(t) landed; STAGE(t+1) stays IN FLIGHT) -> s_barrier -> compute(cur)
// -> s_barrier}. The old __syncthreads() drained vmcnt(0) every body,
// serializing the just-issued prefetch's full HBM/L2 latency after compute
// (m97 barrier-drain pathology; T4 fix measured +38-73% on GEMM).
// vmcnt(4): outstanding per wave = STAGE(t)[4 oldest] + STAGE(t+1)[4 newest].
// Overwrite hazard: end-of-body barrier ensures all waves finished reading
// buf nxt (body t-1) before STAGE(t+1) writes it. Math identical to v6b.
// ---------------------------------------------------------------------------
__global__ __launch_bounds__(256) void attn_mfma(
    const unsigned short* __restrict__ Qb,
    const unsigned short* __restrict__ Kb,
    const unsigned short* __restrict__ Vtg,
    unsigned short* __restrict__ Yb)
{
    __shared__ __align__(16) unsigned short Ks[2][64 * 64];
    __shared__ __align__(16) unsigned short Vs[2][64 * 64];

    const int tid = threadIdx.x;
    const int w = tid >> 6, l = tid & 63;
    const int l31 = l & 31, hi = l >> 5, l7 = l & 7;
    const int dd = blockIdx.x;
    const int bid = (dd & 7) * 64 + (dd >> 3);   // T1 XCD remap (512%8==0)
    const int qc = bid & 15, h = (bid >> 4) & 15, b = bid >> 8;
    const int qrow = b * L_ + qc * 128 + w * 32;

    const int sub = l >> 3;
    const int scc = (l & 7) ^ sub;               // pre-swizzled source chunk
    const unsigned short* ksrc = Kb  + (size_t)(b * L_) * 1024 + h * HD_ + scc * 8;
    const unsigned short* vsrc = Vtg + (size_t)(b * D_ + h * HD_) * 2048 + scc * 8;

#define STAGE(jj, bb) do {                                                    \
    _Pragma("unroll")                                                         \
    for (int i_ = 0; i_ < 2; ++i_) {                                          \
        const int rowK = w * 16 + i_ * 8 + sub;                               \
        __builtin_amdgcn_global_load_lds(                                     \
            (const __attribute__((address_space(1))) void*)                   \
                (ksrc + (size_t)((jj) * 64 + rowK) * 1024),                   \
            (__attribute__((address_space(3))) void*)                         \
                (&Ks[bb][w * 1024 + i_ * 512]), 16, 0, 0);                    \
        __builtin_amdgcn_global_load_lds(                                     \
            (const __attribute__((address_space(1))) void*)                   \
                (vsrc + (size_t)rowK * 2048 + (jj) * 64),                     \
            (__attribute__((address_space(3))) void*)                         \
                (&Vs[bb][w * 1024 + i_ * 512]), 16, 0, 0);                    \
    }                                                                         \
} while (0)

    // Q fragments (B-operand, 32x32x16): col q = l31, k = dh*16 + hi*8 + j.
    // Q pre-scaled by 0.125*log2(e) in the QKV-proj epilogue.
    bf16x8 qa[4];
    #pragma unroll
    for (int dh = 0; dh < 4; ++dh)
        qa[dh] = *(const bf16x8*)
            (Qb + (size_t)(qrow + l31) * D_ + h * HD_ + dh * 16 + hi * 8);

    const f32x16 z16 = {0.f,0.f,0.f,0.f,0.f,0.f,0.f,0.f,
                        0.f,0.f,0.f,0.f,0.f,0.f,0.f,0.f};
    f32x16 o2[2], lacc;
    o2[0] = z16; o2[1] = z16; lacc = z16;

    const short one_s = (short)0x3F80;  // bf16 1.0
    const bf16x8 ones = {one_s, one_s, one_s, one_s, one_s, one_s, one_s, one_s};

#define ATT_BODY(BUF, TNEXT, NBUF, DOSTG) do {                                \
    if (DOSTG) {                                                              \
        STAGE(TNEXT, NBUF);                                                   \
        asm volatile("s_waitcnt vmcnt(4)" ::: "memory");                      \
    } else {                                                                  \
        asm volatile("s_waitcnt vmcnt(0)" ::: "memory");                      \
    }                                                                         \
    __builtin_amdgcn_s_barrier();                                             \
    const unsigned short* Kc = &Ks[BUF][0];                                   \
    const unsigned short* Vc = &Vs[BUF][0];                                   \
    bf16x8 kbf[2][4];                                                         \
    _Pragma("unroll")                                                         \
    for (int kk = 0; kk < 2; ++kk)                                            \
        _Pragma("unroll")                                                     \
        for (int dh = 0; dh < 4; ++dh)                                        \
            kbf[kk][dh] = *(const bf16x8*)                                    \
                (Kc + (kk * 32 + l31) * 64 + (((2 * dh + hi) ^ l7) * 8));     \
    f32x16 s2[2];                                                             \
    __builtin_amdgcn_s_setprio(1);                                            \
    _Pragma("unroll")                                                         \
    for (int kk = 0; kk < 2; ++kk) {                                          \
        s2[kk] = MFMA32(kbf[kk][0], qa[0], z16);                              \
        s2[kk] = MFMA32(kbf[kk][1], qa[1], s2[kk]);                           \
        s2[kk] = MFMA32(kbf[kk][2], qa[2], s2[kk]);                           \
        s2[kk] = MFMA32(kbf[kk][3], qa[3], s2[kk]);                           \
    }                                                                         \
    __builtin_amdgcn_s_setprio(0);                                            \
    _Pragma("unroll")                                                         \
    for (int kk = 0; kk < 2; ++kk)                                            \
        _Pragma("unroll")                                                     \
        for (int r = 0; r < 16; ++r)                                          \
            s2[kk][r] = __builtin_exp2f(s2[kk][r]);                           \
    bf16x8 pa[4];                                                             \
    _Pragma("unroll")                                                         \
    for (int ks = 0; ks < 4; ++ks) {                                          \
        const int kk = ks >> 1, R = 8 * (ks & 1);                             \
        unsigned d0 = pkbf(s2[kk][R + 0], s2[kk][R + 1]);                     \
        unsigned d1 = pkbf(s2[kk][R + 2], s2[kk][R + 3]);                     \
        unsigned d2 = pkbf(s2[kk][R + 4], s2[kk][R + 5]);                     \
        unsigned d3 = pkbf(s2[kk][R + 6], s2[kk][R + 7]);                     \
        asm volatile("v_permlane32_swap_b32 %0, %1" : "+v"(d0), "+v"(d2));    \
        asm volatile("v_permlane32_swap_b32 %0, %1" : "+v"(d1), "+v"(d3));    \
        union { unsigned u[4]; bf16x8 v; } pk_;                               \
        pk_.u[0] = d0; pk_.u[1] = d1; pk_.u[2] = d2; pk_.u[3] = d3;           \
        pa[ks] = pk_.v;                                                       \
    }                                                                         \
    bf16x8 vbf[2][4];                                                         \
    _Pragma("unroll")                                                         \
    for (int dt = 0; dt < 2; ++dt)                                            \
        _Pragma("unroll")                                                     \
        for (int ks = 0; ks < 4; ++ks)                                        \
            vbf[dt][ks] = *(const bf16x8*)                                    \
                (Vc + (dt * 32 + l31) * 64 + (((2 * ks + hi) ^ l7) * 8));     \
    __builtin_amdgcn_s_setprio(1);                                            \
    _Pragma("unroll")                                                         \
    for (int dt = 0; dt < 2; ++dt)                                            \
        _Pragma("unroll")                                                     \
        for (int ks = 0; ks < 4; ++ks)                                        \
            o2[dt] = MFMA32(pa[ks], vbf[dt][ks], o2[dt]);                     \
    _Pragma("unroll")                                                         \
    for (int ks = 0; ks < 4; ++ks)                                            \
        lacc = MFMA32(pa[ks], ones, lacc);                                    \
    __builtin_amdgcn_s_setprio(0);                                            \
    __builtin_amdgcn_s_barrier();                                             \
} while (0)

    STAGE(0, 0);

    #pragma unroll 1
    for (int t = 0; t < L_ / 64; t += 2) {
        ATT_BODY(0, t + 1, 1, true);
        ATT_BODY(1, t + 2, 0, (t + 2 < L_ / 64));
    }
#undef ATT_BODY
#undef STAGE

    // epilogue: rows q = qrow + (r&3)+8*(r>>2)+4*hi, cols d = dt*32 + l31
    #pragma unroll
    for (int r = 0; r < 16; ++r) {
        const float inv = 1.f / lacc[r];
        const int row = qrow + (r & 3) + 8 * (r >> 2) + 4 * hi;
        #pragma unroll
        for (int dt = 0; dt < 2; ++dt)
            Yb[(size_t)row * D_ + h * HD_ + dt * 32 + l31] =
                f2bf(o2[dt][r] * inv);
    }
}

// ---------------------------------------------------------------------------
extern "C" void kernel_launch(void* const* d_in, const int* in_sizes, int n_in,
                              void* d_out, int out_size, void* d_ws, size_t ws_size,
                              hipStream_t stream)
{
    const float* x   = (const float*)d_in[0];
    const float* Wq  = (const float*)d_in[1];
    const float* bq  = (const float*)d_in[2];
    const float* Wkv = (const float*)d_in[3];
    const float* bkv = (const float*)d_in[4];
    const float* Wo  = (const float*)d_in[5];
    const float* bo  = (const float*)d_in[6];
    float* out = (float*)d_out;

    const int M = B_ * L_;  // 4096
    unsigned short* ws = (unsigned short*)d_ws;
    unsigned short* xb   = ws;                          // 4M
    unsigned short* Wqt  = xb   + (size_t)M * D_;       // 1M  \ adjacent =
    unsigned short* Wkvt = Wqt  + (size_t)D_ * D_;      // 2M  / Bt[3072][1024]
    unsigned short* Wot  = Wkvt + (size_t)2 * D_ * D_;  // 1M
    unsigned short* Qb   = Wot  + (size_t)D_ * D_;      // 4M
    unsigned short* Kb   = Qb   + (size_t)M * D_;       // 4M
    unsigned short* Vtg  = Kb   + (size_t)M * D_;       // 4M
    unsigned short* Yb   = Vtg  + (size_t)B_ * D_ * L_; // 4M

    const float QSCL = 0.125f * 1.44269504089f;  // 1/sqrt(HD) * log2(e)

    // prep: x -> bf16; all weight transposes in one launch
    convert_bf16<<<2048, 256, 0, stream>>>(x, xb, M * D_ / 4);
    prep_w<<<dim3(32, 32, 4), 256, 0, stream>>>(Wq, Wkv, Wo, Wqt, Wkvt, Wot);

    // fused QKV projection, 256^2 8-phase (192 blocks); V written transposed
    gemm_qkv8<<<dim3(192), 512, 0, stream>>>(xb, Wqt, bq, bkv, Qb, Kb, Vtg, QSCL);

    // flash attention -> Yb bf16 [M][D]
    attn_mfma<<<dim3(B_ * H_ * (L_ / 128)), 256, 0, stream>>>(Qb, Kb, Vtg, Yb);

    // out = Yb@Wo + bo (fp32 out)
    gemm_bt<<<dim3(D_ / 128, M / 128), 256, 0, stream>>>(Yb, Wot, bo, out, M, D_, D_);
}

// Round 12
// 131.118 us; speedup vs baseline: 1.3238x; 1.0737x over previous
//
#include <hip/hip_runtime.h>

#define B_  2
#define L_  2048
#define D_  1024
#define H_  16
#define HD_ 64

typedef __attribute__((ext_vector_type(8))) short bf16x8;
typedef __attribute__((ext_vector_type(4))) float f32x4;

#define MFMA16(a, b, c) __builtin_amdgcn_mfma_f32_16x16x32_bf16(a, b, c, 0, 0, 0)

__device__ __forceinline__ unsigned short f2bf(float f) {
    union { float f; unsigned u; } v; v.f = f;
    unsigned r = v.u + 0x7FFFu + ((v.u >> 16) & 1u);
    return (unsigned short)(r >> 16);
}

// ---------------------------------------------------------------------------
// Merged prep: z<4 -> weight transposes (fp32 [K][N] -> bf16 [N][K]);
// z==4 -> x fp32 -> bf16 (grid-stride over the 32x32 block slab).
// ---------------------------------------------------------------------------
__global__ __launch_bounds__(256) void prep_all(
    const float* __restrict__ x,
    const float* __restrict__ Wq, const float* __restrict__ Wkv,
    const float* __restrict__ Wo,
    unsigned short* __restrict__ xb,
    unsigned short* __restrict__ Wqt, unsigned short* __restrict__ Wkvt,
    unsigned short* __restrict__ Wot)
{
    const int z = blockIdx.z;
    if (z == 4) {
        const int bidl = blockIdx.y * 32 + blockIdx.x;   // 0..1023
        const int n4 = B_ * L_ * D_ / 4;
        for (int i = bidl * 256 + threadIdx.x; i < n4; i += 1024 * 256) {
            float4 v = *(const float4*)(x + (size_t)i * 4);
            ushort4 u;
            u.x = f2bf(v.x); u.y = f2bf(v.y); u.z = f2bf(v.z); u.w = f2bf(v.w);
            *(ushort4*)(xb + (size_t)i * 4) = u;
        }
        return;
    }
    __shared__ float t[32][33];
    const float* W;  unsigned short* Wt;  int N, nc;
    if (z == 0)      { W = Wq;  Wt = Wqt;  N = 1024; nc = 0; }
    else if (z == 1) { W = Wo;  Wt = Wot;  N = 1024; nc = 0; }
    else             { W = Wkv; Wt = Wkvt; N = 2048; nc = (z - 2) * 1024; }
    const int tx = threadIdx.x & 31, ty = threadIdx.x >> 5;
    const int n0 = nc + blockIdx.x * 32, k0 = blockIdx.y * 32;
    #pragma unroll
    for (int r = 0; r < 4; ++r)
        t[ty + r * 8][tx] = W[(size_t)(k0 + ty + r * 8) * N + n0 + tx];
    __syncthreads();
    #pragma unroll
    for (int r = 0; r < 4; ++r)
        Wt[(size_t)(n0 + ty + r * 8) * 1024 + k0 + tx] = f2bf(t[tx][ty + r * 8]);
}

// ---------------------------------------------------------------------------
// Fused QKV projection, 256x256 tile, 8-phase pipelined schedule (T2+T3+T4+T5).
// Q (scaled) -> Qb, K -> dense Kb, V -> Vtg transposed. (unchanged from R7)
// ---------------------------------------------------------------------------
__global__ __launch_bounds__(512, 1) void gemm_qkv8(
    const unsigned short* __restrict__ A,    // xb [4096][1024]
    const unsigned short* __restrict__ Bt,   // Wqkvt [3072][1024]
    const float* __restrict__ bq, const float* __restrict__ bkv,
    unsigned short* __restrict__ Qb, unsigned short* __restrict__ Kb,
    unsigned short* __restrict__ Vtg, float qscl)
{
    const int KDIM = 1024, NT = 16;  // K-tiles of 64
    __shared__ __align__(16) unsigned short lds[65536];  // 128 KiB

    const int tid = threadIdx.x;
    const int w = tid >> 6, l = tid & 63, g = l >> 4, ln = l & 15;
    const int wm = (w >> 2) & 1, wn = w & 3;

    const int lin = blockIdx.x;
    const int wg = (lin & 7) * 24 + (lin >> 3);
    const int by = wg / 12, bx = wg % 12;
    const int m0 = by * 256, n0 = bx * 256;

    const int sr8 = w * 8 + (l >> 3);
    const int sc  = (l & 7) ^ ((l >> 3) & 7);
    const unsigned short* Asrc = A  + (size_t)m0 * KDIM + sc * 8;
    const unsigned short* Bsrc = Bt + (size_t)n0 * KDIM + sc * 8;

#define SLOT_A(d, h) (lds + ((d) * 2 + (h)) * 8192)
#define SLOT_B(d, h) (lds + 32768 + ((d) * 2 + (h)) * 8192)

#define STG(slotp, srcp, hh, kt_) do {                                        \
    _Pragma("unroll")                                                         \
    for (int r_ = 0; r_ < 2; ++r_) {                                          \
        const int row_ = (hh) * 128 + r_ * 64 + sr8;                          \
        __builtin_amdgcn_global_load_lds(                                     \
            (const __attribute__((address_space(1))) void*)                   \
                ((srcp) + (size_t)row_ * KDIM + (kt_) * 64),                  \
            (__attribute__((address_space(3))) void*)                         \
                ((slotp) + r_ * 4096 + w * 512 + l * 8),                      \
            16, 0, 0);                                                        \
    }                                                                         \
} while (0)

    f32x4 acc[8][4];
    #pragma unroll
    for (int i = 0; i < 8; ++i)
        #pragma unroll
        for (int j = 0; j < 4; ++j) acc[i][j] = (f32x4){0.f, 0.f, 0.f, 0.f};

    bf16x8 aR[4][2], bB0[2][2], bB1[2][2];

    STG(SLOT_A(0, 0), Asrc, 0, 0);
    STG(SLOT_B(0, 1), Bsrc, 1, 0);
    STG(SLOT_A(0, 1), Asrc, 1, 0);
    STG(SLOT_B(0, 0), Bsrc, 0, 0);
    STG(SLOT_A(1, 0), Asrc, 0, 1);
    STG(SLOT_B(1, 1), Bsrc, 1, 1);

    #pragma unroll 1
    for (int kt = 0; kt < NT; ++kt) {
        const int cur = kt & 1, nxt = cur ^ 1;
        asm volatile("s_waitcnt vmcnt(4)" ::: "memory");
        __builtin_amdgcn_s_barrier();

        // ---- phase A ----
        #pragma unroll
        for (int mi = 0; mi < 4; ++mi)
            #pragma unroll
            for (int kc = 0; kc < 2; ++kc) {
                const int rho = wm * 64 + mi * 16 + ln, c = kc * 4 + g;
                aR[mi][kc] = *(const bf16x8*)
                    (SLOT_A(cur, 0) + rho * 64 + ((c ^ (rho & 7)) * 8));
            }
        #pragma unroll
        for (int ni = 0; ni < 2; ++ni)
            #pragma unroll
            for (int kc = 0; kc < 2; ++kc) {
                const int rho = wn * 32 + ni * 16 + ln, c = kc * 4 + g;
                bB0[ni][kc] = *(const bf16x8*)
                    (SLOT_B(cur, 0) + rho * 64 + ((c ^ (rho & 7)) * 8));
            }
        if (kt + 1 < NT) STG(SLOT_A(nxt, 1), Asrc, 1, kt + 1);
        __builtin_amdgcn_s_barrier();
        asm volatile("s_waitcnt lgkmcnt(0)" ::: "memory");
        __builtin_amdgcn_s_setprio(1);
        #pragma unroll
        for (int mi = 0; mi < 4; ++mi)
            #pragma unroll
            for (int ni = 0; ni < 2; ++ni) {
                acc[mi][ni] = MFMA16(aR[mi][0], bB0[ni][0], acc[mi][ni]);
                acc[mi][ni] = MFMA16(aR[mi][1], bB0[ni][1], acc[mi][ni]);
            }
        __builtin_amdgcn_s_setprio(0);
        __builtin_amdgcn_s_barrier();

        // ---- phase B ----
        #pragma unroll
        for (int ni = 0; ni < 2; ++ni)
            #pragma unroll
            for (int kc = 0; kc < 2; ++kc) {
                const int rho = wn * 32 + ni * 16 + ln, c = kc * 4 + g;
                bB1[ni][kc] = *(const bf16x8*)
                    (SLOT_B(cur, 1) + rho * 64 + ((c ^ (rho & 7)) * 8));
            }
        if (kt + 1 < NT) STG(SLOT_B(nxt, 0), Bsrc, 0, kt + 1);
        __builtin_amdgcn_s_barrier();
        asm volatile("s_waitcnt lgkmcnt(0)" ::: "memory");
        __builtin_amdgcn_s_setprio(1);
        #pragma unroll
        for (int mi = 0; mi < 4; ++mi)
            #pragma unroll
            for (int ni = 0; ni < 2; ++ni) {
                acc[mi][2 + ni] = MFMA16(aR[mi][0], bB1[ni][0], acc[mi][2 + ni]);
                acc[mi][2 + ni] = MFMA16(aR[mi][1], bB1[ni][1], acc[mi][2 + ni]);
            }
        __builtin_amdgcn_s_setprio(0);
        __builtin_amdgcn_s_barrier();

        // ---- phase C ----
        #pragma unroll
        for (int mi = 0; mi < 4; ++mi)
            #pragma unroll
            for (int kc = 0; kc < 2; ++kc) {
                const int rho = wm * 64 + mi * 16 + ln, c = kc * 4 + g;
                aR[mi][kc] = *(const bf16x8*)
                    (SLOT_A(cur, 1) + rho * 64 + ((c ^ (rho & 7)) * 8));
            }
        if (kt + 2 < NT) STG(SLOT_A(cur, 0), Asrc, 0, kt + 2);
        __builtin_amdgcn_s_barrier();
        asm volatile("s_waitcnt lgkmcnt(0)" ::: "memory");
        __builtin_amdgcn_s_setprio(1);
        #pragma unroll
        for (int mi = 0; mi < 4; ++mi)
            #pragma unroll
            for (int ni = 0; ni < 2; ++ni) {
                acc[4 + mi][2 + ni] = MFMA16(aR[mi][0], bB1[ni][0], acc[4 + mi][2 + ni]);
                acc[4 + mi][2 + ni] = MFMA16(aR[mi][1], bB1[ni][1], acc[4 + mi][2 + ni]);
            }
        __builtin_amdgcn_s_setprio(0);
        __builtin_amdgcn_s_barrier();

        // ---- phase D ----
        if (kt + 2 < NT) STG(SLOT_B(cur, 1), Bsrc, 1, kt + 2);
        __builtin_amdgcn_s_barrier();
        __builtin_amdgcn_s_setprio(1);
        #pragma unroll
        for (int mi = 0; mi < 4; ++mi)
            #pragma unroll
            for (int ni = 0; ni < 2; ++ni) {
                acc[4 + mi][ni] = MFMA16(aR[mi][0], bB0[ni][0], acc[4 + mi][ni]);
                acc[4 + mi][ni] = MFMA16(aR[mi][1], bB0[ni][1], acc[4 + mi][ni]);
            }
        __builtin_amdgcn_s_setprio(0);
        __builtin_amdgcn_s_barrier();
    }
#undef STG
#undef SLOT_A
#undef SLOT_B

    const int region = n0 >> 10;  // 0=Q, 1=K, 2=V
    if (region == 2) {
        #pragma unroll
        for (int nh = 0; nh < 2; ++nh)
            #pragma unroll
            for (int ni = 0; ni < 2; ++ni) {
                const int d = n0 - 2048 + nh * 128 + wn * 32 + ni * 16 + ln;
                const float bv = bkv[1024 + d];
                #pragma unroll
                for (int mh = 0; mh < 2; ++mh)
                    #pragma unroll
                    for (int mi = 0; mi < 4; ++mi) {
                        const int tok = m0 + mh * 128 + wm * 64 + mi * 16 + g * 4;
                        const int bb = tok >> 11, t4 = tok & 2047;
                        const f32x4 av = acc[mh * 4 + mi][nh * 2 + ni];
                        ushort4 p4;
                        p4.x = f2bf(av[0] + bv); p4.y = f2bf(av[1] + bv);
                        p4.z = f2bf(av[2] + bv); p4.w = f2bf(av[3] + bv);
                        *(ushort4*)(Vtg + ((size_t)bb * 1024 + d) * 2048 + t4) = p4;
                    }
            }
    } else {
        const int isQ = (region == 0);
        const float osc = isQ ? qscl : 1.f;
        #pragma unroll
        for (int nh = 0; nh < 2; ++nh)
            #pragma unroll
            for (int ni = 0; ni < 2; ++ni) {
                const int col = n0 + nh * 128 + wn * 32 + ni * 16 + ln;
                const float bv = isQ ? bq[col] : bkv[col - 1024];
                const int ck = isQ ? col : col - 1024;
                #pragma unroll
                for (int mh = 0; mh < 2; ++mh)
                    #pragma unroll
                    for (int mi = 0; mi < 4; ++mi) {
                        const int row = m0 + mh * 128 + wm * 64 + mi * 16 + g * 4;
                        const f32x4 av = acc[mh * 4 + mi][nh * 2 + ni];
                        #pragma unroll
                        for (int r = 0; r < 4; ++r) {
                            const float vout = (av[r] + bv) * osc;
                            if (isQ)
                                Qb[(size_t)(row + r) * 1024 + ck] = f2bf(vout);
                            else
                                Kb[(size_t)(row + r) * 1024 + ck] = f2bf(vout);
                        }
                    }
            }
    }
}

// ---------------------------------------------------------------------------
// Out-projection GEMM, retiled 128x64 (was 128x128): grid 512 blocks = 2/CU
// (was 256 = 1/CU, 1 wave/SIMD latency-exposed). Same m97 per-wave pipeline;
// compute-per-staged-byte unchanged. T1 XCD remap: each XCD owns 4 row-bands
// -> A rows + full Wot L2-resident.
// ---------------------------------------------------------------------------
__global__ __launch_bounds__(256) void gemm_bt2(
    const unsigned short* __restrict__ A,    // Yb [4096][1024]
    const unsigned short* __restrict__ Bt,   // Wot [1024][1024]
    const float* __restrict__ bias,
    float* __restrict__ Cout)
{
    const int N = 1024, K = 1024;
    __shared__ __align__(16) unsigned short As[128 * 32];
    __shared__ __align__(16) unsigned short Bs[64 * 32];
    const int tid = threadIdx.x;
    const int w = tid >> 6, l = tid & 63, g = l >> 4, ln = l & 15;
    const int wm = w >> 1, wn = w & 1;
    const int dd = blockIdx.x;
    const int bid = (dd & 7) * 64 + (dd >> 3);   // T1 remap (512%8==0)
    const int m0 = (bid >> 4) * 128, n0 = (bid & 15) * 64;

    f32x4 acc[4][2];
    #pragma unroll
    for (int i = 0; i < 4; ++i)
        #pragma unroll
        for (int j = 0; j < 2; ++j) acc[i][j] = (f32x4){0.f, 0.f, 0.f, 0.f};

    const char* Ab = (const char*)A;
    const char* Bb = (const char*)Bt;
    const size_t strideK = (size_t)K * 2;

    // B staging map: thread -> row tid>>2, 16B chunk (tid&3)
    const int brow = tid >> 2, bcb = (tid & 3) * 16;

    for (int k0 = 0; k0 < K; k0 += 32) {
        #pragma unroll
        for (int i = 0; i < 2; ++i) {
            const int b = w * 2048 + i * 1024 + l * 16;
            const int row = b >> 6, cb = b & 63;
            __builtin_amdgcn_global_load_lds(
                (const __attribute__((address_space(1))) void*)
                    (Ab + (size_t)(m0 + row) * strideK + (size_t)k0 * 2 + cb),
                (__attribute__((address_space(3))) void*)
                    ((char*)As + w * 2048 + i * 1024),
                16, 0, 0);
        }
        __builtin_amdgcn_global_load_lds(
            (const __attribute__((address_space(1))) void*)
                (Bb + (size_t)(n0 + brow) * strideK + (size_t)k0 * 2 + bcb),
            (__attribute__((address_space(3))) void*)
                ((char*)Bs + tid * 16),
            16, 0, 0);
        __syncthreads();
        bf16x8 af[4], bfr[2];
        #pragma unroll
        for (int m = 0; m < 4; ++m)
            af[m] = *(const bf16x8*)(As + (wm * 64 + m * 16 + ln) * 32 + g * 8);
        #pragma unroll
        for (int n = 0; n < 2; ++n)
            bfr[n] = *(const bf16x8*)(Bs + (wn * 32 + n * 16 + ln) * 32 + g * 8);
        #pragma unroll
        for (int m = 0; m < 4; ++m)
            #pragma unroll
            for (int n = 0; n < 2; ++n)
                acc[m][n] = MFMA16(af[m], bfr[n], acc[m][n]);
        __syncthreads();
    }

    #pragma unroll
    for (int n = 0; n < 2; ++n) {
        const int col = n0 + wn * 32 + n * 16 + ln;
        const float bv = bias[col];
        #pragma unroll
        for (int m = 0; m < 4; ++m) {
            const int row = m0 + wm * 64 + m * 16 + g * 4;
            #pragma unroll
            for (int r = 0; r < 4; ++r)
                Cout[(size_t)(row + r) * N + col] = acc[m][n][r] + bv;
        }
    }
}

// ---------------------------------------------------------------------------
// bf16 MFMA flash attention v5 (R7 verbatim -- best measured: 67.9 us).
// 16x16x32 MFMA; K from dense Kb; K-loop unrolled by 2 (compile-time buffer
// constants); P-tile 8B-granularity swizzle; pack via v_perm.
// ---------------------------------------------------------------------------
__global__ __launch_bounds__(256) void attn_mfma(
    const unsigned short* __restrict__ Qb,
    const unsigned short* __restrict__ Kb,
    const unsigned short* __restrict__ Vtg,
    unsigned short* __restrict__ Yb)
{
    __shared__ __align__(16) unsigned short Ks[2][64 * 64];
    __shared__ __align__(16) unsigned short Vs[2][64 * 64];
    __shared__ __align__(16) unsigned short Pl[4][32 * 64];

    const int tid = threadIdx.x;
    const int w = tid >> 6, l = tid & 63, g = l >> 4, ln = l & 15;
    const int dd = blockIdx.x;
    const int bid = (dd & 7) * 64 + (dd >> 3);   // T1 XCD remap (512%8==0)
    const int qc = bid & 15, h = (bid >> 4) & 15, b = bid >> 8;
    const int qrow = b * L_ + qc * 128 + w * 32;

    const int sub = l >> 3;
    const int scc = (l & 7) ^ sub;               // pre-swizzled source chunk
    const unsigned short* ksrc = Kb  + (size_t)(b * L_) * 1024 + h * HD_ + scc * 8;
    const unsigned short* vsrc = Vtg + (size_t)(b * D_ + h * HD_) * 2048 + scc * 8;

#define STAGE(jj, bb) do {                                                    \
    _Pragma("unroll")                                                         \
    for (int i_ = 0; i_ < 2; ++i_) {                                          \
        const int rowK = w * 16 + i_ * 8 + sub;                               \
        __builtin_amdgcn_global_load_lds(                                     \
            (const __attribute__((address_space(1))) void*)                   \
                (ksrc + (size_t)((jj) * 64 + rowK) * 1024),                   \
            (__attribute__((address_space(3))) void*)                         \
                (&Ks[bb][w * 1024 + i_ * 512]), 16, 0, 0);                    \
        __builtin_amdgcn_global_load_lds(                                     \
            (const __attribute__((address_space(1))) void*)                   \
                (vsrc + (size_t)rowK * 2048 + (jj) * 64),                     \
            (__attribute__((address_space(3))) void*)                         \
                (&Vs[bb][w * 1024 + i_ * 512]), 16, 0, 0);                    \
    }                                                                         \
} while (0)

    bf16x8 qa[2][2];
    #pragma unroll
    for (int qt = 0; qt < 2; ++qt)
        #pragma unroll
        for (int c = 0; c < 2; ++c)
            qa[qt][c] = *(const bf16x8*)
                (Qb + (size_t)(qrow + qt * 16 + ln) * D_ + h * HD_ + c * 32 + g * 8);

    f32x4 o[2][4], lacc[2];
    #pragma unroll
    for (int qt = 0; qt < 2; ++qt) {
        #pragma unroll
        for (int dt = 0; dt < 4; ++dt) o[qt][dt] = (f32x4){0.f, 0.f, 0.f, 0.f};
        lacc[qt] = (f32x4){0.f, 0.f, 0.f, 0.f};
    }
    const short one_s = (short)0x3F80;  // bf16 1.0
    const bf16x8 ones = {one_s, one_s, one_s, one_s, one_s, one_s, one_s, one_s};

    unsigned short* Pw = &Pl[w][0];
    const int swzl = (ln & 7) << 3;     // K/V read XOR (16B granularity)
    const int swp  = (ln & 7) << 1;     // P chunk XOR (8B granularity, bits 1-3)

#define ATT_BODY(BUF, TNEXT, NBUF, DOSTG) do {                                \
    if (DOSTG) STAGE(TNEXT, NBUF);                                            \
    const unsigned short* Kc = &Ks[BUF][0];                                   \
    const unsigned short* Vc = &Vs[BUF][0];                                   \
    bf16x8 kb[4][2];                                                          \
    _Pragma("unroll")                                                         \
    for (int kt = 0; kt < 4; ++kt)                                            \
        _Pragma("unroll")                                                     \
        for (int c = 0; c < 2; ++c)                                           \
            kb[kt][c] = *(const bf16x8*)                                      \
                (Kc + (kt * 16 + ln) * 64 + ((c * 32 + g * 8) ^ swzl));       \
    f32x4 s[2][4];                                                            \
    const f32x4 z = (f32x4){0.f, 0.f, 0.f, 0.f};                              \
    __builtin_amdgcn_s_setprio(1);                                            \
    _Pragma("unroll")                                                         \
    for (int qt = 0; qt < 2; ++qt)                                            \
        _Pragma("unroll")                                                     \
        for (int kt = 0; kt < 4; ++kt) {                                      \
            f32x4 t0 = MFMA16(kb[kt][0], qa[qt][0], z);                       \
            s[qt][kt] = MFMA16(kb[kt][1], qa[qt][1], t0);                     \
        }                                                                     \
    __builtin_amdgcn_s_setprio(0);                                            \
    _Pragma("unroll")                                                         \
    for (int qt = 0; qt < 2; ++qt) {                                          \
        const int prow = (qt * 16 + ln) * 64;                                 \
        _Pragma("unroll")                                                     \
        for (int kt = 0; kt < 4; ++kt) {                                      \
            union { float f; unsigned u; } c0, c1, c2u, c3;                   \
            c0.f = __builtin_exp2f(s[qt][kt][0]);                             \
            c1.f = __builtin_exp2f(s[qt][kt][1]);                             \
            c2u.f = __builtin_exp2f(s[qt][kt][2]);                            \
            c3.f = __builtin_exp2f(s[qt][kt][3]);                             \
            uint2 pk;                                                         \
            pk.x = __builtin_amdgcn_perm(c1.u, c0.u, 0x07060302u);            \
            pk.y = __builtin_amdgcn_perm(c3.u, c2u.u, 0x07060302u);           \
            *(uint2*)(Pw + prow + (((kt * 4 + g) ^ swp) << 2)) = pk;          \
        }                                                                     \
    }                                                                         \
    bf16x8 pa[2][2], vb[4][2];                                                \
    _Pragma("unroll")                                                         \
    for (int qt = 0; qt < 2; ++qt)                                            \
        _Pragma("unroll")                                                     \
        for (int c2 = 0; c2 < 2; ++c2)                                        \
            pa[qt][c2] = *(const bf16x8*)                                     \
                (Pw + (qt * 16 + ln) * 64 + (((c2 * 8 + g * 2) ^ swp) << 2)); \
    _Pragma("unroll")                                                         \
    for (int dt = 0; dt < 4; ++dt)                                            \
        _Pragma("unroll")                                                     \
        for (int c2 = 0; c2 < 2; ++c2)                                        \
            vb[dt][c2] = *(const bf16x8*)                                     \
                (Vc + (dt * 16 + ln) * 64 + ((c2 * 32 + g * 8) ^ swzl));      \
    __builtin_amdgcn_s_setprio(1);                                            \
    _Pragma("unroll")                                                         \
    for (int qt = 0; qt < 2; ++qt) {                                          \
        lacc[qt] = MFMA16(pa[qt][0], ones, lacc[qt]);                         \
        lacc[qt] = MFMA16(pa[qt][1], ones, lacc[qt]);                         \
        _Pragma("unroll")                                                     \
        for (int dt = 0; dt < 4; ++dt) {                                      \
            o[qt][dt] = MFMA16(pa[qt][0], vb[dt][0], o[qt][dt]);              \
            o[qt][dt] = MFMA16(pa[qt][1], vb[dt][1], o[qt][dt]);              \
        }                                                                     \
    }                                                                         \
    __builtin_amdgcn_s_setprio(0);                                            \
} while (0)

    STAGE(0, 0);
    __syncthreads();

    #pragma unroll 1
    for (int t = 0; t < L_ / 64; t += 2) {
        ATT_BODY(0, t + 1, 1, true);
        __syncthreads();
        ATT_BODY(1, t + 2, 0, (t + 2 < L_ / 64));
        __syncthreads();
    }
#undef ATT_BODY
#undef STAGE

    #pragma unroll
    for (int qt = 0; qt < 2; ++qt)
        #pragma unroll
        for (int r = 0; r < 4; ++r) {
            const float inv = 1.f / lacc[qt][r];
            const int row = qrow + qt * 16 + g * 4 + r;
            #pragma unroll
            for (int dt = 0; dt < 4; ++dt)
                Yb[(size_t)row * D_ + h * HD_ + dt * 16 + ln] =
                    f2bf(o[qt][dt][r] * inv);
        }
}

// ---------------------------------------------------------------------------
extern "C" void kernel_launch(void* const* d_in, const int* in_sizes, int n_in,
                              void* d_out, int out_size, void* d_ws, size_t ws_size,
                              hipStream_t stream)
{
    const float* x   = (const float*)d_in[0];
    const float* Wq  = (const float*)d_in[1];
    const float* bq  = (const float*)d_in[2];
    const float* Wkv = (const float*)d_in[3];
    const float* bkv = (const float*)d_in[4];
    const float* Wo  = (const float*)d_in[5];
    const float* bo  = (const float*)d_in[6];
    float* out = (float*)d_out;

    const int M = B_ * L_;  // 4096
    unsigned short* ws = (unsigned short*)d_ws;
    unsigned short* xb   = ws;                          // 8MB
    unsigned short* Wqt  = xb   + (size_t)M * D_;       // 2MB \ adjacent =
    unsigned short* Wkvt = Wqt  + (size_t)D_ * D_;      // 4MB / Bt[3072][1024]
    unsigned short* Wot  = Wkvt + (size_t)2 * D_ * D_;  // 2MB
    unsigned short* Qb   = Wot  + (size_t)D_ * D_;      // 8MB
    unsigned short* Kb   = Qb   + (size_t)M * D_;       // 8MB
    unsigned short* Vtg  = Kb   + (size_t)M * D_;       // 8MB
    unsigned short* Yb   = Vtg  + (size_t)B_ * D_ * L_; // 8MB

    const float QSCL = 0.125f * 1.44269504089f;  // 1/sqrt(HD) * log2(e)

    // prep: x -> bf16 + all weight transposes, one launch
    prep_all<<<dim3(32, 32, 5), 256, 0, stream>>>(
        x, Wq, Wkv, Wo, xb, Wqt, Wkvt, Wot);

    // fused QKV projection, 256^2 8-phase (192 blocks); V written transposed
    gemm_qkv8<<<dim3(192), 512, 0, stream>>>(xb, Wqt, bq, bkv, Qb, Kb, Vtg, QSCL);

    // flash attention -> Yb bf16 [M][D]
    attn_mfma<<<dim3(B_ * H_ * (L_ / 128)), 256, 0, stream>>>(Qb, Kb, Vtg, Yb);

    // out = Yb@Wo + bo (fp32 out), 128x64 tiles, 512 blocks
    gemm_bt2<<<dim3(512), 256, 0, stream>>>(Yb, Wot, bo, out);
}

// Round 13
// 123.673 us; speedup vs baseline: 1.4035x; 1.0602x over previous
//
#include <hip/hip_runtime.h>

#define B_  2
#define L_  2048
#define D_  1024
#define H_  16
#define HD_ 64

typedef __attribute__((ext_vector_type(8))) short bf16x8;
typedef __attribute__((ext_vector_type(4))) float f32x4;

#define MFMA16(a, b, c) __builtin_amdgcn_mfma_f32_16x16x32_bf16(a, b, c, 0, 0, 0)

__device__ __forceinline__ unsigned short f2bf(float f) {
    union { float f; unsigned u; } v; v.f = f;
    unsigned r = v.u + 0x7FFFu + ((v.u >> 16) & 1u);
    return (unsigned short)(r >> 16);
}

// ---------------------------------------------------------------------------
// Merged prep: z<4 -> weight transposes (fp32 [K][N] -> bf16 [N][K]);
// z==4 -> x fp32 -> bf16 (grid-stride over the 32x32 block slab).
// ---------------------------------------------------------------------------
__global__ __launch_bounds__(256) void prep_all(
    const float* __restrict__ x,
    const float* __restrict__ Wq, const float* __restrict__ Wkv,
    const float* __restrict__ Wo,
    unsigned short* __restrict__ xb,
    unsigned short* __restrict__ Wqt, unsigned short* __restrict__ Wkvt,
    unsigned short* __restrict__ Wot)
{
    const int z = blockIdx.z;
    if (z == 4) {
        const int bidl = blockIdx.y * 32 + blockIdx.x;   // 0..1023
        const int n4 = B_ * L_ * D_ / 4;
        for (int i = bidl * 256 + threadIdx.x; i < n4; i += 1024 * 256) {
            float4 v = *(const float4*)(x + (size_t)i * 4);
            ushort4 u;
            u.x = f2bf(v.x); u.y = f2bf(v.y); u.z = f2bf(v.z); u.w = f2bf(v.w);
            *(ushort4*)(xb + (size_t)i * 4) = u;
        }
        return;
    }
    __shared__ float t[32][33];
    const float* W;  unsigned short* Wt;  int N, nc;
    if (z == 0)      { W = Wq;  Wt = Wqt;  N = 1024; nc = 0; }
    else if (z == 1) { W = Wo;  Wt = Wot;  N = 1024; nc = 0; }
    else             { W = Wkv; Wt = Wkvt; N = 2048; nc = (z - 2) * 1024; }
    const int tx = threadIdx.x & 31, ty = threadIdx.x >> 5;
    const int n0 = nc + blockIdx.x * 32, k0 = blockIdx.y * 32;
    #pragma unroll
    for (int r = 0; r < 4; ++r)
        t[ty + r * 8][tx] = W[(size_t)(k0 + ty + r * 8) * N + n0 + tx];
    __syncthreads();
    #pragma unroll
    for (int r = 0; r < 4; ++r)
        Wt[(size_t)(n0 + ty + r * 8) * 1024 + k0 + tx] = f2bf(t[tx][ty + r * 8]);
}

// ---------------------------------------------------------------------------
// Fused QKV projection, 256x256 tile, 8-phase pipelined schedule (T2+T3+T4+T5).
// Q (scaled) -> Qb, K -> dense Kb, V -> Vtg transposed. (unchanged from R12)
// ---------------------------------------------------------------------------
__global__ __launch_bounds__(512, 1) void gemm_qkv8(
    const unsigned short* __restrict__ A,    // xb [4096][1024]
    const unsigned short* __restrict__ Bt,   // Wqkvt [3072][1024]
    const float* __restrict__ bq, const float* __restrict__ bkv,
    unsigned short* __restrict__ Qb, unsigned short* __restrict__ Kb,
    unsigned short* __restrict__ Vtg, float qscl)
{
    const int KDIM = 1024, NT = 16;  // K-tiles of 64
    __shared__ __align__(16) unsigned short lds[65536];  // 128 KiB

    const int tid = threadIdx.x;
    const int w = tid >> 6, l = tid & 63, g = l >> 4, ln = l & 15;
    const int wm = (w >> 2) & 1, wn = w & 3;

    const int lin = blockIdx.x;
    const int wg = (lin & 7) * 24 + (lin >> 3);
    const int by = wg / 12, bx = wg % 12;
    const int m0 = by * 256, n0 = bx * 256;

    const int sr8 = w * 8 + (l >> 3);
    const int sc  = (l & 7) ^ ((l >> 3) & 7);
    const unsigned short* Asrc = A  + (size_t)m0 * KDIM + sc * 8;
    const unsigned short* Bsrc = Bt + (size_t)n0 * KDIM + sc * 8;

#define SLOT_A(d, h) (lds + ((d) * 2 + (h)) * 8192)
#define SLOT_B(d, h) (lds + 32768 + ((d) * 2 + (h)) * 8192)

#define STG(slotp, srcp, hh, kt_) do {                                        \
    _Pragma("unroll")                                                         \
    for (int r_ = 0; r_ < 2; ++r_) {                                          \
        const int row_ = (hh) * 128 + r_ * 64 + sr8;                          \
        __builtin_amdgcn_global_load_lds(                                     \
            (const __attribute__((address_space(1))) void*)                   \
                ((srcp) + (size_t)row_ * KDIM + (kt_) * 64),                  \
            (__attribute__((address_space(3))) void*)                         \
                ((slotp) + r_ * 4096 + w * 512 + l * 8),                      \
            16, 0, 0);                                                        \
    }                                                                         \
} while (0)

    f32x4 acc[8][4];
    #pragma unroll
    for (int i = 0; i < 8; ++i)
        #pragma unroll
        for (int j = 0; j < 4; ++j) acc[i][j] = (f32x4){0.f, 0.f, 0.f, 0.f};

    bf16x8 aR[4][2], bB0[2][2], bB1[2][2];

    STG(SLOT_A(0, 0), Asrc, 0, 0);
    STG(SLOT_B(0, 1), Bsrc, 1, 0);
    STG(SLOT_A(0, 1), Asrc, 1, 0);
    STG(SLOT_B(0, 0), Bsrc, 0, 0);
    STG(SLOT_A(1, 0), Asrc, 0, 1);
    STG(SLOT_B(1, 1), Bsrc, 1, 1);

    #pragma unroll 1
    for (int kt = 0; kt < NT; ++kt) {
        const int cur = kt & 1, nxt = cur ^ 1;
        asm volatile("s_waitcnt vmcnt(4)" ::: "memory");
        __builtin_amdgcn_s_barrier();

        // ---- phase A ----
        #pragma unroll
        for (int mi = 0; mi < 4; ++mi)
            #pragma unroll
            for (int kc = 0; kc < 2; ++kc) {
                const int rho = wm * 64 + mi * 16 + ln, c = kc * 4 + g;
                aR[mi][kc] = *(const bf16x8*)
                    (SLOT_A(cur, 0) + rho * 64 + ((c ^ (rho & 7)) * 8));
            }
        #pragma unroll
        for (int ni = 0; ni < 2; ++ni)
            #pragma unroll
            for (int kc = 0; kc < 2; ++kc) {
                const int rho = wn * 32 + ni * 16 + ln, c = kc * 4 + g;
                bB0[ni][kc] = *(const bf16x8*)
                    (SLOT_B(cur, 0) + rho * 64 + ((c ^ (rho & 7)) * 8));
            }
        if (kt + 1 < NT) STG(SLOT_A(nxt, 1), Asrc, 1, kt + 1);
        __builtin_amdgcn_s_barrier();
        asm volatile("s_waitcnt lgkmcnt(0)" ::: "memory");
        __builtin_amdgcn_s_setprio(1);
        #pragma unroll
        for (int mi = 0; mi < 4; ++mi)
            #pragma unroll
            for (int ni = 0; ni < 2; ++ni) {
                acc[mi][ni] = MFMA16(aR[mi][0], bB0[ni][0], acc[mi][ni]);
                acc[mi][ni] = MFMA16(aR[mi][1], bB0[ni][1], acc[mi][ni]);
            }
        __builtin_amdgcn_s_setprio(0);
        __builtin_amdgcn_s_barrier();

        // ---- phase B ----
        #pragma unroll
        for (int ni = 0; ni < 2; ++ni)
            #pragma unroll
            for (int kc = 0; kc < 2; ++kc) {
                const int rho = wn * 32 + ni * 16 + ln, c = kc * 4 + g;
                bB1[ni][kc] = *(const bf16x8*)
                    (SLOT_B(cur, 1) + rho * 64 + ((c ^ (rho & 7)) * 8));
            }
        if (kt + 1 < NT) STG(SLOT_B(nxt, 0), Bsrc, 0, kt + 1);
        __builtin_amdgcn_s_barrier();
        asm volatile("s_waitcnt lgkmcnt(0)" ::: "memory");
        __builtin_amdgcn_s_setprio(1);
        #pragma unroll
        for (int mi = 0; mi < 4; ++mi)
            #pragma unroll
            for (int ni = 0; ni < 2; ++ni) {
                acc[mi][2 + ni] = MFMA16(aR[mi][0], bB1[ni][0], acc[mi][2 + ni]);
                acc[mi][2 + ni] = MFMA16(aR[mi][1], bB1[ni][1], acc[mi][2 + ni]);
            }
        __builtin_amdgcn_s_setprio(0);
        __builtin_amdgcn_s_barrier();

        // ---- phase C ----
        #pragma unroll
        for (int mi = 0; mi < 4; ++mi)
            #pragma unroll
            for (int kc = 0; kc < 2; ++kc) {
                const int rho = wm * 64 + mi * 16 + ln, c = kc * 4 + g;
                aR[mi][kc] = *(const bf16x8*)
                    (SLOT_A(cur, 1) + rho * 64 + ((c ^ (rho & 7)) * 8));
            }
        if (kt + 2 < NT) STG(SLOT_A(cur, 0), Asrc, 0, kt + 2);
        __builtin_amdgcn_s_barrier();
        asm volatile("s_waitcnt lgkmcnt(0)" ::: "memory");
        __builtin_amdgcn_s_setprio(1);
        #pragma unroll
        for (int mi = 0; mi < 4; ++mi)
            #pragma unroll
            for (int ni = 0; ni < 2; ++ni) {
                acc[4 + mi][2 + ni] = MFMA16(aR[mi][0], bB1[ni][0], acc[4 + mi][2 + ni]);
                acc[4 + mi][2 + ni] = MFMA16(aR[mi][1], bB1[ni][1], acc[4 + mi][2 + ni]);
            }
        __builtin_amdgcn_s_setprio(0);
        __builtin_amdgcn_s_barrier();

        // ---- phase D ----
        if (kt + 2 < NT) STG(SLOT_B(cur, 1), Bsrc, 1, kt + 2);
        __builtin_amdgcn_s_barrier();
        __builtin_amdgcn_s_setprio(1);
        #pragma unroll
        for (int mi = 0; mi < 4; ++mi)
            #pragma unroll
            for (int ni = 0; ni < 2; ++ni) {
                acc[4 + mi][ni] = MFMA16(aR[mi][0], bB0[ni][0], acc[4 + mi][ni]);
                acc[4 + mi][ni] = MFMA16(aR[mi][1], bB0[ni][1], acc[4 + mi][ni]);
            }
        __builtin_amdgcn_s_setprio(0);
        __builtin_amdgcn_s_barrier();
    }
#undef STG
#undef SLOT_A
#undef SLOT_B

    const int region = n0 >> 10;  // 0=Q, 1=K, 2=V
    if (region == 2) {
        #pragma unroll
        for (int nh = 0; nh < 2; ++nh)
            #pragma unroll
            for (int ni = 0; ni < 2; ++ni) {
                const int d = n0 - 2048 + nh * 128 + wn * 32 + ni * 16 + ln;
                const float bv = bkv[1024 + d];
                #pragma unroll
                for (int mh = 0; mh < 2; ++mh)
                    #pragma unroll
                    for (int mi = 0; mi < 4; ++mi) {
                        const int tok = m0 + mh * 128 + wm * 64 + mi * 16 + g * 4;
                        const int bb = tok >> 11, t4 = tok & 2047;
                        const f32x4 av = acc[mh * 4 + mi][nh * 2 + ni];
                        ushort4 p4;
                        p4.x = f2bf(av[0] + bv); p4.y = f2bf(av[1] + bv);
                        p4.z = f2bf(av[2] + bv); p4.w = f2bf(av[3] + bv);
                        *(ushort4*)(Vtg + ((size_t)bb * 1024 + d) * 2048 + t4) = p4;
                    }
            }
    } else {
        const int isQ = (region == 0);
        const float osc = isQ ? qscl : 1.f;
        #pragma unroll
        for (int nh = 0; nh < 2; ++nh)
            #pragma unroll
            for (int ni = 0; ni < 2; ++ni) {
                const int col = n0 + nh * 128 + wn * 32 + ni * 16 + ln;
                const float bv = isQ ? bq[col] : bkv[col - 1024];
                const int ck = isQ ? col : col - 1024;
                #pragma unroll
                for (int mh = 0; mh < 2; ++mh)
                    #pragma unroll
                    for (int mi = 0; mi < 4; ++mi) {
                        const int row = m0 + mh * 128 + wm * 64 + mi * 16 + g * 4;
                        const f32x4 av = acc[mh * 4 + mi][nh * 2 + ni];
                        #pragma unroll
                        for (int r = 0; r < 4; ++r) {
                            const float vout = (av[r] + bv) * osc;
                            if (isQ)
                                Qb[(size_t)(row + r) * 1024 + ck] = f2bf(vout);
                            else
                                Kb[(size_t)(row + r) * 1024 + ck] = f2bf(vout);
                        }
                    }
            }
    }
}

// ---------------------------------------------------------------------------
// Out-projection GEMM v2: 128x64 tile, BK=64 (16 iters, barriers halved),
// qkv8's proven swizzle (pre-swizzled staging chunks + c^(rho&7) reads) --
// conflict-free b128 at the 128B row stride. 512 blocks, T1 remap.
// ---------------------------------------------------------------------------
__global__ __launch_bounds__(256) void gemm_bt2(
    const unsigned short* __restrict__ A,    // Yb [4096][1024]
    const unsigned short* __restrict__ Bt,   // Wot [1024][1024]
    const float* __restrict__ bias,
    float* __restrict__ Cout)
{
    const int N = 1024, K = 1024;
    __shared__ __align__(16) unsigned short As[128 * 64];
    __shared__ __align__(16) unsigned short Bs[64 * 64];
    const int tid = threadIdx.x;
    const int w = tid >> 6, l = tid & 63, g = l >> 4, ln = l & 15;
    const int wm = w >> 1, wn = w & 1;
    const int dd = blockIdx.x;
    const int bid = (dd & 7) * 64 + (dd >> 3);   // T1 remap (512%8==0)
    const int m0 = (bid >> 4) * 128, n0 = (bid & 15) * 64;

    const int sr8 = w * 8 + (l >> 3);            // 0..31
    const int sc  = (l & 7) ^ ((l >> 3) & 7);    // pre-swizzled source chunk
    const unsigned short* Asrc = A  + (size_t)m0 * K + sc * 8;
    const unsigned short* Bsrc = Bt + (size_t)n0 * K + sc * 8;

    f32x4 acc[4][2];
    #pragma unroll
    for (int i = 0; i < 4; ++i)
        #pragma unroll
        for (int j = 0; j < 2; ++j) acc[i][j] = (f32x4){0.f, 0.f, 0.f, 0.f};

    for (int k0 = 0; k0 < K; k0 += 64) {
        #pragma unroll
        for (int r_ = 0; r_ < 4; ++r_)
            __builtin_amdgcn_global_load_lds(
                (const __attribute__((address_space(1))) void*)
                    (Asrc + (size_t)(r_ * 32 + sr8) * K + k0),
                (__attribute__((address_space(3))) void*)
                    (As + r_ * 2048 + w * 512 + l * 8),
                16, 0, 0);
        #pragma unroll
        for (int r_ = 0; r_ < 2; ++r_)
            __builtin_amdgcn_global_load_lds(
                (const __attribute__((address_space(1))) void*)
                    (Bsrc + (size_t)(r_ * 32 + sr8) * K + k0),
                (__attribute__((address_space(3))) void*)
                    (Bs + r_ * 2048 + w * 512 + l * 8),
                16, 0, 0);
        __syncthreads();
        bf16x8 af[4][2], bfr[2][2];
        #pragma unroll
        for (int mi = 0; mi < 4; ++mi)
            #pragma unroll
            for (int kc = 0; kc < 2; ++kc) {
                const int rho = wm * 64 + mi * 16 + ln, c = kc * 4 + g;
                af[mi][kc] = *(const bf16x8*)
                    (As + rho * 64 + ((c ^ (rho & 7)) * 8));
            }
        #pragma unroll
        for (int ni = 0; ni < 2; ++ni)
            #pragma unroll
            for (int kc = 0; kc < 2; ++kc) {
                const int rho = wn * 32 + ni * 16 + ln, c = kc * 4 + g;
                bfr[ni][kc] = *(const bf16x8*)
                    (Bs + rho * 64 + ((c ^ (rho & 7)) * 8));
            }
        __builtin_amdgcn_s_setprio(1);
        #pragma unroll
        for (int mi = 0; mi < 4; ++mi)
            #pragma unroll
            for (int ni = 0; ni < 2; ++ni) {
                acc[mi][ni] = MFMA16(af[mi][0], bfr[ni][0], acc[mi][ni]);
                acc[mi][ni] = MFMA16(af[mi][1], bfr[ni][1], acc[mi][ni]);
            }
        __builtin_amdgcn_s_setprio(0);
        __syncthreads();
    }

    #pragma unroll
    for (int n = 0; n < 2; ++n) {
        const int col = n0 + wn * 32 + n * 16 + ln;
        const float bv = bias[col];
        #pragma unroll
        for (int m = 0; m < 4; ++m) {
            const int row = m0 + wm * 64 + m * 16 + g * 4;
            #pragma unroll
            for (int r = 0; r < 4; ++r)
                Cout[(size_t)(row + r) * N + col] = acc[m][n][r] + bv;
        }
    }
}

// ---------------------------------------------------------------------------
// bf16 MFMA flash attention v9 = v5 + T15-analog pipeline.
// Body split: S-phase(t) = {kb, QK, vb->regs, exp, pack, P-write[slot t&1]};
// O-phase(t-1) = {pa-read[slot (t-1)&1], ones-MFMA, PV with vb regs (t-1)}.
// O(t-1) runs inside body t: its 20 MFMAs are independent of body t's
// exp/pack VALU chain -> MFMA pipe fills while VALU runs. P-tile (Pl) is
// per-wave double-buffered (wave-private -> no extra barriers); V fragments
// carried in registers across one body (vbA/vbB, static indexing).
// Math identical to v5; only order + buffering changed. LDS 64KB (2 blk/CU).
// ---------------------------------------------------------------------------
__global__ __launch_bounds__(256, 2) void attn_mfma(
    const unsigned short* __restrict__ Qb,
    const unsigned short* __restrict__ Kb,
    const unsigned short* __restrict__ Vtg,
    unsigned short* __restrict__ Yb)
{
    __shared__ __align__(16) unsigned short Ks[2][64 * 64];
    __shared__ __align__(16) unsigned short Vs[2][64 * 64];
    __shared__ __align__(16) unsigned short Pl[4][2][32 * 64];

    const int tid = threadIdx.x;
    const int w = tid >> 6, l = tid & 63, g = l >> 4, ln = l & 15;
    const int dd = blockIdx.x;
    const int bid = (dd & 7) * 64 + (dd >> 3);   // T1 XCD remap (512%8==0)
    const int qc = bid & 15, h = (bid >> 4) & 15, b = bid >> 8;
    const int qrow = b * L_ + qc * 128 + w * 32;

    const int sub = l >> 3;
    const int scc = (l & 7) ^ sub;               // pre-swizzled source chunk
    const unsigned short* ksrc = Kb  + (size_t)(b * L_) * 1024 + h * HD_ + scc * 8;
    const unsigned short* vsrc = Vtg + (size_t)(b * D_ + h * HD_) * 2048 + scc * 8;

#define STAGE(jj, bb) do {                                                    \
    _Pragma("unroll")                                                         \
    for (int i_ = 0; i_ < 2; ++i_) {                                          \
        const int rowK = w * 16 + i_ * 8 + sub;                               \
        __builtin_amdgcn_global_load_lds(                                     \
            (const __attribute__((address_space(1))) void*)                   \
                (ksrc + (size_t)((jj) * 64 + rowK) * 1024),                   \
            (__attribute__((address_space(3))) void*)                         \
                (&Ks[bb][w * 1024 + i_ * 512]), 16, 0, 0);                    \
        __builtin_amdgcn_global_load_lds(                                     \
            (const __attribute__((address_space(1))) void*)                   \
                (vsrc + (size_t)rowK * 2048 + (jj) * 64),                     \
            (__attribute__((address_space(3))) void*)                         \
                (&Vs[bb][w * 1024 + i_ * 512]), 16, 0, 0);                    \
    }                                                                         \
} while (0)

    bf16x8 qa[2][2];
    #pragma unroll
    for (int qt = 0; qt < 2; ++qt)
        #pragma unroll
        for (int c = 0; c < 2; ++c)
            qa[qt][c] = *(const bf16x8*)
                (Qb + (size_t)(qrow + qt * 16 + ln) * D_ + h * HD_ + c * 32 + g * 8);

    f32x4 o[2][4], lacc[2];
    #pragma unroll
    for (int qt = 0; qt < 2; ++qt) {
        #pragma unroll
        for (int dt = 0; dt < 4; ++dt) o[qt][dt] = (f32x4){0.f, 0.f, 0.f, 0.f};
        lacc[qt] = (f32x4){0.f, 0.f, 0.f, 0.f};
    }
    const short one_s = (short)0x3F80;  // bf16 1.0
    const bf16x8 ones = {one_s, one_s, one_s, one_s, one_s, one_s, one_s, one_s};

    unsigned short* Pw = &Pl[w][0][0];
    const int swzl = (ln & 7) << 3;     // K/V read XOR (16B granularity)
    const int swp  = (ln & 7) << 1;     // P chunk XOR (8B granularity)

    bf16x8 vbA[4][2], vbB[4][2];        // V frags carried across one body

    // S-phase of body t: kb, QK, vb->VARR, exp, pack, P-write slot PWS
#define S_CORE(BUF, PWS, VARR) do {                                           \
    const unsigned short* Kc = &Ks[BUF][0];                                   \
    const unsigned short* Vc = &Vs[BUF][0];                                   \
    bf16x8 kb[4][2];                                                          \
    _Pragma("unroll")                                                         \
    for (int kt = 0; kt < 4; ++kt)                                            \
        _Pragma("unroll")                                                     \
        for (int c = 0; c < 2; ++c)                                           \
            kb[kt][c] = *(const bf16x8*)                                      \
                (Kc + (kt * 16 + ln) * 64 + ((c * 32 + g * 8) ^ swzl));       \
    f32x4 s[2][4];                                                            \
    const f32x4 z = (f32x4){0.f, 0.f, 0.f, 0.f};                              \
    __builtin_amdgcn_s_setprio(1);                                            \
    _Pragma("unroll")                                                         \
    for (int qt = 0; qt < 2; ++qt)                                            \
        _Pragma("unroll")                                                     \
        for (int kt = 0; kt < 4; ++kt) {                                      \
            f32x4 t0 = MFMA16(kb[kt][0], qa[qt][0], z);                       \
            s[qt][kt] = MFMA16(kb[kt][1], qa[qt][1], t0);                     \
        }                                                                     \
    __builtin_amdgcn_s_setprio(0);                                            \
    _Pragma("unroll")                                                         \
    for (int dt = 0; dt < 4; ++dt)                                            \
        _Pragma("unroll")                                                     \
        for (int c2 = 0; c2 < 2; ++c2)                                        \
            VARR[dt][c2] = *(const bf16x8*)                                   \
                (Vc + (dt * 16 + ln) * 64 + ((c2 * 32 + g * 8) ^ swzl));      \
    _Pragma("unroll")                                                         \
    for (int qt = 0; qt < 2; ++qt) {                                          \
        const int prow = (qt * 16 + ln) * 64;                                 \
        _Pragma("unroll")                                                     \
        for (int kt = 0; kt < 4; ++kt) {                                      \
            union { float f; unsigned u; } c0, c1, c2u, c3;                   \
            c0.f = __builtin_exp2f(s[qt][kt][0]);                             \
            c1.f = __builtin_exp2f(s[qt][kt][1]);                             \
            c2u.f = __builtin_exp2f(s[qt][kt][2]);                            \
            c3.f = __builtin_exp2f(s[qt][kt][3]);                             \
            uint2 pk;                                                         \
            pk.x = __builtin_amdgcn_perm(c1.u, c0.u, 0x07060302u);            \
            pk.y = __builtin_amdgcn_perm(c3.u, c2u.u, 0x07060302u);           \
            *(uint2*)(Pw + (PWS) * 2048 + prow +                              \
                      (((kt * 4 + g) ^ swp) << 2)) = pk;                      \
        }                                                                     \
    }                                                                         \
} while (0)

    // O-phase of body t-1: pa from slot PPWS, PV with PVARR regs
#define O_PHASE(PPWS, PVARR) do {                                             \
    bf16x8 pa[2][2];                                                          \
    _Pragma("unroll")                                                         \
    for (int qt = 0; qt < 2; ++qt)                                            \
        _Pragma("unroll")                                                     \
        for (int c2 = 0; c2 < 2; ++c2)                                        \
            pa[qt][c2] = *(const bf16x8*)                                     \
                (Pw + (PPWS) * 2048 + (qt * 16 + ln) * 64 +                   \
                 (((c2 * 8 + g * 2) ^ swp) << 2));                            \
    __builtin_amdgcn_s_setprio(1);                                            \
    _Pragma("unroll")                                                         \
    for (int qt = 0; qt < 2; ++qt) {                                          \
        lacc[qt] = MFMA16(pa[qt][0], ones, lacc[qt]);                         \
        lacc[qt] = MFMA16(pa[qt][1], ones, lacc[qt]);                         \
        _Pragma("unroll")                                                     \
        for (int dt = 0; dt < 4; ++dt) {                                      \
            o[qt][dt] = MFMA16(pa[qt][0], PVARR[dt][0], o[qt][dt]);           \
            o[qt][dt] = MFMA16(pa[qt][1], PVARR[dt][1], o[qt][dt]);           \
        }                                                                     \
    }                                                                         \
    __builtin_amdgcn_s_setprio(0);                                            \
} while (0)

    STAGE(0, 0);
    __syncthreads();

    // body 0: S only (buf0, P slot0, vbA); stages tile1 -> buf1
    STAGE(1, 1);
    S_CORE(0, 0, vbA);
    __syncthreads();

    // bodies 1..30, pipelined pairs
    #pragma unroll 1
    for (int t = 1; t < 31; t += 2) {
        STAGE(t + 1, 0);                 // tile t+1 -> buf0
        O_PHASE(0, vbA);                 // finish body t-1
        S_CORE(1, 1, vbB);               // body t (buf1)
        __syncthreads();
        if (t + 2 < 32) STAGE(t + 2, 1); // tile t+2 -> buf1
        O_PHASE(1, vbB);                 // finish body t
        S_CORE(0, 0, vbA);               // body t+1 (buf0)
        __syncthreads();
    }

    // body 31: O(30) + S(31) (buf1); then drain O(31)
    O_PHASE(0, vbA);
    S_CORE(1, 1, vbB);
    O_PHASE(1, vbB);
#undef O_PHASE
#undef S_CORE
#undef STAGE

    #pragma unroll
    for (int qt = 0; qt < 2; ++qt)
        #pragma unroll
        for (int r = 0; r < 4; ++r) {
            const float inv = 1.f / lacc[qt][r];
            const int row = qrow + qt * 16 + g * 4 + r;
            #pragma unroll
            for (int dt = 0; dt < 4; ++dt)
                Yb[(size_t)row * D_ + h * HD_ + dt * 16 + ln] =
                    f2bf(o[qt][dt][r] * inv);
        }
}

// ---------------------------------------------------------------------------
extern "C" void kernel_launch(void* const* d_in, const int* in_sizes, int n_in,
                              void* d_out, int out_size, void* d_ws, size_t ws_size,
                              hipStream_t stream)
{
    const float* x   = (const float*)d_in[0];
    const float* Wq  = (const float*)d_in[1];
    const float* bq  = (const float*)d_in[2];
    const float* Wkv = (const float*)d_in[3];
    const float* bkv = (const float*)d_in[4];
    const float* Wo  = (const float*)d_in[5];
    const float* bo  = (const float*)d_in[6];
    float* out = (float*)d_out;

    const int M = B_ * L_;  // 4096
    unsigned short* ws = (unsigned short*)d_ws;
    unsigned short* xb   = ws;                          // 8MB
    unsigned short* Wqt  = xb   + (size_t)M * D_;       // 2MB \ adjacent =
    unsigned short* Wkvt = Wqt  + (size_t)D_ * D_;      // 4MB / Bt[3072][1024]
    unsigned short* Wot  = Wkvt + (size_t)2 * D_ * D_;  // 2MB
    unsigned short* Qb   = Wot  + (size_t)D_ * D_;      // 8MB
    unsigned short* Kb   = Qb   + (size_t)M * D_;       // 8MB
    unsigned short* Vtg  = Kb   + (size_t)M * D_;       // 8MB
    unsigned short* Yb   = Vtg  + (size_t)B_ * D_ * L_; // 8MB

    const float QSCL = 0.125f * 1.44269504089f;  // 1/sqrt(HD) * log2(e)

    // prep: x -> bf16 + all weight transposes, one launch
    prep_all<<<dim3(32, 32, 5), 256, 0, stream>>>(
        x, Wq, Wkv, Wo, xb, Wqt, Wkvt, Wot);

    // fused QKV projection, 256^2 8-phase (192 blocks); V written transposed
    gemm_qkv8<<<dim3(192), 512, 0, stream>>>(xb, Wqt, bq, bkv, Qb, Kb, Vtg, QSCL);

    // flash attention -> Yb bf16 [M][D]
    attn_mfma<<<dim3(B_ * H_ * (L_ / 128)), 256, 0, stream>>>(Qb, Kb, Vtg, Yb);

    // out = Yb@Wo + bo (fp32 out), 128x64 tiles, BK=64, 512 blocks
    gemm_bt2<<<dim3(512), 256, 0, stream>>>(Yb, Wot, bo, out);
}